// Round 20
// baseline (258.438 us; speedup 1.0000x reference)
//
#include <hip/hip_runtime.h>

#define B_ 2
#define L_ 2048
#define D_ 1024
#define H_ 16
#define DH_ 64

typedef float f32x4 __attribute__((ext_vector_type(4)));
typedef __bf16 bf16x8 __attribute__((ext_vector_type(8)));

__device__ __forceinline__ ushort f2bf(float f) {
  unsigned u = __float_as_uint(f);
  u += 0x7fffu + ((u >> 16) & 1u);
  return (ushort)(u >> 16);
}
__device__ __forceinline__ float bf2f(ushort h) {
  return __uint_as_float(((unsigned)h) << 16);
}

__device__ __forceinline__ void gload_lds16(const void* g, void* l) {
  __builtin_amdgcn_global_load_lds(
      (const __attribute__((address_space(1))) unsigned*)g,
      (__attribute__((address_space(3))) unsigned*)l, 16, 0, 0);
}

__device__ __forceinline__ float gelu_f(float v) {
  return 0.5f * v * (1.0f + tanhf(0.7978845608f * (v + 0.044715f * v * v * v)));
}

// ---------------- cast f32 -> bf16, all four weights in one launch ----------------
__global__ __launch_bounds__(256) void cast_all_kernel(const float* __restrict__ w0,
                                                       const float* __restrict__ w1,
                                                       const float* __restrict__ w2,
                                                       const float* __restrict__ w3,
                                                       ushort* __restrict__ o0,
                                                       ushort* __restrict__ o1,
                                                       ushort* __restrict__ o2,
                                                       ushort* __restrict__ o3) {
  int i = blockIdx.x * 256 + threadIdx.x;
  const float* src;
  ushort* dst;
  int j = i;
  if (j < 786432) { src = w0; dst = o0; }
  else if (j < 786432 + 262144) { j -= 786432; src = w1; dst = o1; }
  else if (j < 786432 + 262144 + 1048576) { j -= 786432 + 262144; src = w2; dst = o2; }
  else { j -= 786432 + 262144 + 1048576; src = w3; dst = o3; }
  float4 v = ((const float4*)src)[j];
  ushort4 o;
  o.x = f2bf(v.x); o.y = f2bf(v.y); o.z = f2bf(v.z); o.w = f2bf(v.w);
  ((ushort4*)dst)[j] = o;
}

// ---------------- RMSNorm (f32 in, bf16 out), one block per row of 1024 ----------------
__global__ __launch_bounds__(256) void rmsnorm_kernel(const float* __restrict__ x,
                                                      const float* __restrict__ scale,
                                                      ushort* __restrict__ out) {
  int row = blockIdx.x, t = threadIdx.x;
  float4 v = ((const float4*)(x + (size_t)row * D_))[t];
  float ss = v.x * v.x + v.y * v.y + v.z * v.z + v.w * v.w;
#pragma unroll
  for (int d = 1; d < 64; d <<= 1) ss += __shfl_xor(ss, d);
  __shared__ float wsum[4];
  if ((t & 63) == 0) wsum[t >> 6] = ss;
  __syncthreads();
  float tot = wsum[0] + wsum[1] + wsum[2] + wsum[3];
  float r = rsqrtf(tot * (1.0f / D_) + 1e-6f);
  float4 sc = ((const float4*)scale)[t];
  ushort4 o;
  o.x = f2bf(v.x * sc.x * r); o.y = f2bf(v.y * sc.y * r);
  o.z = f2bf(v.z * sc.z * r); o.w = f2bf(v.w * sc.w * r);
  ((ushort4*)(out + (size_t)row * D_))[t] = o;
}

// -------- fused: x1 = x + sum(4 bf16 partials); x1b=bf16(x1); xn=rmsnorm(x1,norm2) ----
// One block per row. Replaces the out-proj reduce AND the second rmsnorm pass.
__global__ __launch_bounds__(256) void reduce_out_rmsnorm_kernel(
    const ushort* __restrict__ P, const float* __restrict__ x,
    const float* __restrict__ scale, ushort* __restrict__ x1b,
    ushort* __restrict__ xn) {
  int row = blockIdx.x, t = threadIdx.x;
  size_t i4 = (size_t)row * 256 + t;
  float4 v = ((const float4*)x)[i4];
#pragma unroll
  for (int z = 0; z < 4; z++) {
    ushort4 p = ((const ushort4*)(P + (size_t)z * 4194304))[i4];
    v.x += bf2f(p.x); v.y += bf2f(p.y); v.z += bf2f(p.z); v.w += bf2f(p.w);
  }
  ushort4 o1;
  o1.x = f2bf(v.x); o1.y = f2bf(v.y); o1.z = f2bf(v.z); o1.w = f2bf(v.w);
  ((ushort4*)x1b)[i4] = o1;
  float ss = v.x * v.x + v.y * v.y + v.z * v.z + v.w * v.w;
#pragma unroll
  for (int d = 1; d < 64; d <<= 1) ss += __shfl_xor(ss, d);
  __shared__ float wsum[4];
  if ((t & 63) == 0) wsum[t >> 6] = ss;
  __syncthreads();
  float tot = wsum[0] + wsum[1] + wsum[2] + wsum[3];
  float r = rsqrtf(tot * (1.0f / D_) + 1e-6f);
  float4 sc = ((const float4*)scale)[t];
  ushort4 o;
  o.x = f2bf(v.x * sc.x * r); o.y = f2bf(v.y * sc.y * r);
  o.z = f2bf(v.z * sc.z * r); o.w = f2bf(v.w * sc.w * r);
  ((ushort4*)(xn + (size_t)row * D_))[t] = o;
}

// ============ 256x256 8-phase NT GEMM (m194-m201 template, plain HIP) ============
// Split-K via gridDim.z: block z covers K range [z*Klen,(z+1)*Klen).
// EPI 0: bf16 store. EPI 2: bf16 gelu. EPI 3: bf16 raw partial at z*M*N offset.
template <int EPI, int XR, int XC>
__global__ __launch_bounds__(512, 2) void gemm256(const ushort* __restrict__ A,
                                                  const ushort* __restrict__ Bw,
                                                  void* __restrict__ Cout,
                                                  int M, int N, int K, int Klen) {
  __shared__ __align__(16) ushort Als[2][2][128 * 64];
  __shared__ __align__(16) ushort Bls[2][2][128 * 64];
  const int tid = threadIdx.x;
  const int lane = tid & 63;
  const int w = tid >> 6;
  const int wm = w >> 2, wn = w & 3;
  const int fr = lane & 15, fg = lane >> 4;
  const int bid = blockIdx.y * gridDim.x + blockIdx.x;
  const int xcd = bid & 7, i0 = bid >> 3;
  const int CR = gridDim.x / XR, CC = gridDim.y / XC;
  const int rt = (xcd % XR) * CR + (i0 % CR);
  const int ct = (xcd / XR) * CC + (i0 / CR);
  const int row0 = rt * 256, col0 = ct * 256;
  const int koff = blockIdx.z * Klen;
  const ushort* Ab = A + (size_t)row0 * K + koff;
  const ushort* Bb = Bw + (size_t)col0 * K + koff;
  const int srow = tid >> 3;
  const int sxor = ((tid & 7) ^ (srow & 7)) * 8;

  f32x4 acc[8][4];
  f32x4 zero = {0.f, 0.f, 0.f, 0.f};
#pragma unroll
  for (int m = 0; m < 8; m++)
#pragma unroll
    for (int n = 0; n < 4; n++) acc[m][n] = zero;

  auto stageA = [&](int buf, int half, int kt) {
#pragma unroll
    for (int i = 0; i < 2; i++)
      gload_lds16(Ab + (size_t)(half * 128 + i * 64 + srow) * K + kt + sxor,
                  &Als[buf][half][i * 4096 + tid * 8]);
  };
  auto stageB = [&](int buf, int half, int kt) {
#pragma unroll
    for (int i = 0; i < 2; i++)
      gload_lds16(Bb + (size_t)(half * 128 + i * 64 + srow) * K + kt + sxor,
                  &Bls[buf][half][i * 4096 + tid * 8]);
  };
  const int nt = Klen >> 6;
  stageA(0, 0, 0); stageB(0, 0, 0); stageB(0, 1, 0); stageA(0, 1, 0);
  asm volatile("s_waitcnt vmcnt(0)" ::: "memory");
  __builtin_amdgcn_s_barrier();

  bf16x8 afr[4][2], b0[2][2], b1[2][2];
  for (int t = 0; t < nt; t++) {
    const int cur = t & 1, nxt = cur ^ 1;
    const int kn = (t + 1) << 6;
    const bool more = (t + 1 < nt);
    // phase 0: (0,0)
#pragma unroll
    for (int mf = 0; mf < 4; mf++)
#pragma unroll
      for (int ks = 0; ks < 2; ks++) {
        int r = wm * 64 + mf * 16 + fr;
        afr[mf][ks] = *(const bf16x8*)&Als[cur][0][r * 64 + (((ks * 4 + fg) ^ (r & 7)) << 3)];
      }
#pragma unroll
    for (int nf = 0; nf < 2; nf++)
#pragma unroll
      for (int ks = 0; ks < 2; ks++) {
        int c = wn * 32 + nf * 16 + fr;
        b0[nf][ks] = *(const bf16x8*)&Bls[cur][0][c * 64 + (((ks * 4 + fg) ^ (c & 7)) << 3)];
      }
    if (more) stageA(nxt, 0, kn);
    asm volatile("s_waitcnt vmcnt(4)" ::: "memory");
    __builtin_amdgcn_s_barrier();
    asm volatile("s_waitcnt lgkmcnt(0)" ::: "memory");
    __builtin_amdgcn_sched_barrier(0);
    __builtin_amdgcn_s_setprio(1);
#pragma unroll
    for (int mf = 0; mf < 4; mf++)
#pragma unroll
      for (int nf = 0; nf < 2; nf++)
#pragma unroll
        for (int ks = 0; ks < 2; ks++)
          acc[mf][nf] =
              __builtin_amdgcn_mfma_f32_16x16x32_bf16(afr[mf][ks], b0[nf][ks], acc[mf][nf], 0, 0, 0);
    __builtin_amdgcn_s_setprio(0);
    __builtin_amdgcn_s_barrier();
    // phase 1: (0,1)
#pragma unroll
    for (int nf = 0; nf < 2; nf++)
#pragma unroll
      for (int ks = 0; ks < 2; ks++) {
        int c = wn * 32 + nf * 16 + fr;
        b1[nf][ks] = *(const bf16x8*)&Bls[cur][1][c * 64 + (((ks * 4 + fg) ^ (c & 7)) << 3)];
      }
    if (more) stageB(nxt, 0, kn);
    asm volatile("s_waitcnt vmcnt(4)" ::: "memory");
    __builtin_amdgcn_s_barrier();
    asm volatile("s_waitcnt lgkmcnt(0)" ::: "memory");
    __builtin_amdgcn_sched_barrier(0);
    __builtin_amdgcn_s_setprio(1);
#pragma unroll
    for (int mf = 0; mf < 4; mf++)
#pragma unroll
      for (int nf = 0; nf < 2; nf++)
#pragma unroll
        for (int ks = 0; ks < 2; ks++)
          acc[mf][2 + nf] =
              __builtin_amdgcn_mfma_f32_16x16x32_bf16(afr[mf][ks], b1[nf][ks], acc[mf][2 + nf], 0, 0, 0);
    __builtin_amdgcn_s_setprio(0);
    __builtin_amdgcn_s_barrier();
    // phase 2: (1,1)
#pragma unroll
    for (int mf = 0; mf < 4; mf++)
#pragma unroll
      for (int ks = 0; ks < 2; ks++) {
        int r = wm * 64 + mf * 16 + fr;
        afr[mf][ks] = *(const bf16x8*)&Als[cur][1][r * 64 + (((ks * 4 + fg) ^ (r & 7)) << 3)];
      }
    if (more) stageB(nxt, 1, kn);
    asm volatile("s_waitcnt vmcnt(4)" ::: "memory");
    __builtin_amdgcn_s_barrier();
    asm volatile("s_waitcnt lgkmcnt(0)" ::: "memory");
    __builtin_amdgcn_sched_barrier(0);
    __builtin_amdgcn_s_setprio(1);
#pragma unroll
    for (int mf = 0; mf < 4; mf++)
#pragma unroll
      for (int nf = 0; nf < 2; nf++)
#pragma unroll
        for (int ks = 0; ks < 2; ks++)
          acc[4 + mf][2 + nf] =
              __builtin_amdgcn_mfma_f32_16x16x32_bf16(afr[mf][ks], b1[nf][ks], acc[4 + mf][2 + nf], 0, 0, 0);
    __builtin_amdgcn_s_setprio(0);
    __builtin_amdgcn_s_barrier();
    // phase 3: (1,0)
    if (more) stageA(nxt, 1, kn);
    asm volatile("s_waitcnt vmcnt(4)" ::: "memory");
    __builtin_amdgcn_s_barrier();
    asm volatile("s_waitcnt lgkmcnt(0)" ::: "memory");
    __builtin_amdgcn_sched_barrier(0);
    __builtin_amdgcn_s_setprio(1);
#pragma unroll
    for (int mf = 0; mf < 4; mf++)
#pragma unroll
      for (int nf = 0; nf < 2; nf++)
#pragma unroll
        for (int ks = 0; ks < 2; ks++)
          acc[4 + mf][nf] =
              __builtin_amdgcn_mfma_f32_16x16x32_bf16(afr[mf][ks], b0[nf][ks], acc[4 + mf][nf], 0, 0, 0);
    __builtin_amdgcn_s_setprio(0);
    __builtin_amdgcn_s_barrier();
  }
  const int orow = row0 + wm * 64 + fg * 4;
  const int ocol = col0 + wn * 32 + fr;
  ushort* Pz = (ushort*)Cout + (size_t)blockIdx.z * M * N;
#pragma unroll
  for (int am = 0; am < 8; am++) {
#pragma unroll
    for (int j = 0; j < 4; j++) {
      int r = orow + (am >> 2) * 128 + (am & 3) * 16 + j;
#pragma unroll
      for (int an = 0; an < 4; an++) {
        int cidx = ocol + (an >> 1) * 128 + (an & 1) * 16;
        size_t idx = (size_t)r * N + cidx;
        float v = acc[am][an][j];
        if (EPI == 0) {
          ((ushort*)Cout)[idx] = f2bf(v);
        } else if (EPI == 2) {
          ((ushort*)Cout)[idx] = f2bf(gelu_f(v));
        } else {
          Pz[idx] = f2bf(v);
        }
      }
    }
  }
}

// ---------------- split-K=4 reduce: out = bf16resid + P0+P1+P2+P3 (bf16 partials) ------
__global__ __launch_bounds__(256) void reduce_down4_kernel(const ushort* __restrict__ P,
                                                           const ushort* __restrict__ residb,
                                                           float* __restrict__ out) {
  int i = blockIdx.x * 256 + threadIdx.x;
  ushort4 r = ((const ushort4*)residb)[i];
  float4 o;
  o.x = bf2f(r.x); o.y = bf2f(r.y); o.z = bf2f(r.z); o.w = bf2f(r.w);
#pragma unroll
  for (int z = 0; z < 4; z++) {
    ushort4 p = ((const ushort4*)(P + (size_t)z * 4194304))[i];
    o.x += bf2f(p.x); o.y += bf2f(p.y); o.z += bf2f(p.z); o.w += bf2f(p.w);
  }
  ((float4*)out)[i] = o;
}

// ---------------- RoPE + cosine-sim scaling; Q pre-scaled by log2(e) ----------------
__global__ __launch_bounds__(256) void rope_kernel(const ushort* __restrict__ qkv,
                                                   const float* __restrict__ pos,
                                                   const float* __restrict__ pos_orig,
                                                   const float* __restrict__ timep,
                                                   const float* __restrict__ qk_scale,
                                                   ushort* __restrict__ qr,
                                                   ushort* __restrict__ kr) {
  int gw = (blockIdx.x * 256 + threadIdx.x) >> 6;
  int lane = threadIdx.x & 63;
  int h = gw & 15;
  int row = gw >> 4;
  int b = row >> 11;
  int l = row & (L_ - 1);
  float qv = bf2f(qkv[(size_t)row * 3072 + h * 64 + lane]);
  float kv = bf2f(qkv[(size_t)row * 3072 + 1024 + h * 64 + lane]);
  float c = 1.0f, s = 0.0f;
  if (lane < 50) {
    int idx = lane < 25 ? lane : lane - 25;
    int sg = idx / 5, d = idx % 5;
    int fi = d * 16 + h;
    float th;
    if (sg == 4) {
      th = timep[row] * __expf(-(float)fi * 0.05756462732485115f);
    } else {
      float fr = 3.14159265358979323846f * __expf((float)fi * 0.028782313662425575f);
      const float* psrc = (sg == 0 || sg == 2) ? pos_orig : pos;
      int comp = (sg < 2) ? 1 : 0;
      th = (2.0f * psrc[(size_t)row * 2 + comp] - 1.0f) * fr;
    }
    s = sinf(th);
    c = cosf(th);
  }
  int partner = lane < 25 ? lane + 25 : lane - 25;
  float qp = __shfl(qv, partner, 64);
  float kp = __shfl(kv, partner, 64);
  float yq, yk;
  if (lane < 25) { yq = qv * c - qp * s; yk = kv * c - kp * s; }
  else if (lane < 50) { yq = qv * c + qp * s; yk = kv * c + kp * s; }
  else { yq = qv; yk = kv; }
  float sq = yq * yq, sk = yk * yk;
#pragma unroll
  for (int d = 1; d < 64; d <<= 1) { sq += __shfl_xor(sq, d); sk += __shfl_xor(sk, d); }
  float scl = sqrtf(qk_scale[h]);
  float qo = yq * (scl * 1.4426950408889634f) * rsqrtf(sq + 1e-6f);
  float ko = yk * scl * rsqrtf(sk + 1e-6f);
  size_t o = ((size_t)(b * 16 + h) * L_ + l) * 64 + lane;
  qr[o] = f2bf(qo);
  kr[o] = f2bf(ko);
}

// ---------------- V transpose ----------------
__global__ __launch_bounds__(256) void vtrans_kernel(const ushort* __restrict__ qkv,
                                                     ushort* __restrict__ vT) {
  __shared__ __align__(16) ushort tile[64][72];
  int t = threadIdx.x;
  int lt = blockIdx.x;
  int bh = blockIdx.y;
  int b = bh >> 4, h = bh & 15;
  int r = t >> 3, c0 = (t & 7) * 8;
#pragma unroll
  for (int half = 0; half < 2; half++) {
    const ushort* src =
        qkv + (size_t)(b * L_ + lt * 64 + r + half * 32) * 3072 + 2048 + h * 64 + c0;
    *(uint4*)&tile[r + half * 32][c0] = *(const uint4*)src;
  }
  __syncthreads();
#pragma unroll
  for (int half = 0; half < 2; half++) {
    int dh = r + half * 32;
    unsigned p0 = (unsigned)tile[c0 + 0][dh] | ((unsigned)tile[c0 + 1][dh] << 16);
    unsigned p1 = (unsigned)tile[c0 + 2][dh] | ((unsigned)tile[c0 + 3][dh] << 16);
    unsigned p2 = (unsigned)tile[c0 + 4][dh] | ((unsigned)tile[c0 + 5][dh] << 16);
    unsigned p3 = (unsigned)tile[c0 + 6][dh] | ((unsigned)tile[c0 + 7][dh] << 16);
    uint4 o; o.x = p0; o.y = p1; o.z = p2; o.w = p3;
    *(uint4*)&vT[((size_t)bh * 64 + dh) * L_ + lt * 64 + c0] = o;
  }
}

// ---------------- Flash attention: packed-P variant (R18 structure) -------------------
__global__ __launch_bounds__(256) void attn_kernel(const ushort* __restrict__ qr,
                                                   const ushort* __restrict__ kr,
                                                   const ushort* __restrict__ vT,
                                                   ushort* __restrict__ attnb) {
  __shared__ __align__(16) ushort Kls[2][64 * 64];
  __shared__ __align__(16) ushort Vls[2][64 * 64];
  __shared__ __align__(16) unsigned Pls2[4][16 * 68];
  const int tid = threadIdx.x, lane = tid & 63, w = tid >> 6;
  const int bid = blockIdx.x;
  const int qp = (bid >> 3) & 15;
  const int bh = (bid & 7) | ((bid >> 7) << 3);
  const int b = bh >> 4;
  const int fr = lane & 15, fg = lane >> 4;
  const ushort* Qb0 = qr + ((size_t)bh * L_ + qp * 128 + w * 16) * 64;
  const ushort* Qb1 = Qb0 + 64 * 64;
  bf16x8 qf0[2], qf1[2];
#pragma unroll
  for (int c = 0; c < 2; c++) {
    qf0[c] = *(const bf16x8*)(Qb0 + fr * 64 + c * 32 + fg * 8);
    qf1[c] = *(const bf16x8*)(Qb1 + fr * 64 + c * 32 + fg * 8);
  }
  const ushort ob[8] = {0x3F80, 0x3F80, 0x3F80, 0x3F80, 0x3F80, 0x3F80, 0x3F80, 0x3F80};
  const bf16x8 ones = *(const bf16x8*)ob;
  f32x4 zero = {0.f, 0.f, 0.f, 0.f};
  f32x4 accO0[4], accO1[4], acc1_0 = zero, acc1_1 = zero;
#pragma unroll
  for (int n = 0; n < 4; n++) { accO0[n] = zero; accO1[n] = zero; }
  const int sr = tid >> 3;
  const int scz = (((tid & 7) ^ (sr & 7)) * 8);
  auto stage = [&](int buf, int kt) {
    gload_lds16(kr + ((size_t)bh * L_ + kt + sr) * 64 + scz, &Kls[buf][tid * 8]);
    gload_lds16(kr + ((size_t)bh * L_ + kt + 32 + sr) * 64 + scz, &Kls[buf][2048 + tid * 8]);
    gload_lds16(vT + ((size_t)bh * 64 + sr) * L_ + kt + scz, &Vls[buf][tid * 8]);
    gload_lds16(vT + ((size_t)bh * 64 + 32 + sr) * L_ + kt + scz, &Vls[buf][2048 + tid * 8]);
  };
  stage(0, 0);
  int cur = 0;
  for (int t = 0; t < (L_ >> 6); t++) {
    asm volatile("s_waitcnt vmcnt(0)" ::: "memory");
    __builtin_amdgcn_s_barrier();
    __builtin_amdgcn_sched_barrier(0);
    if (t + 1 < (L_ >> 6)) stage(cur ^ 1, (t + 1) << 6);
    f32x4 sv0[4], sv1[4];
#pragma unroll
    for (int n = 0; n < 4; n++) { sv0[n] = zero; sv1[n] = zero; }
    __builtin_amdgcn_s_setprio(1);
#pragma unroll
    for (int c = 0; c < 2; c++) {
#pragma unroll
      for (int n = 0; n < 4; n++) {
        bf16x8 kf =
            *(const bf16x8*)&Kls[cur][(n * 16 + fr) * 64 + (((c * 4 + fg) ^ (fr & 7)) << 3)];
        sv0[n] = __builtin_amdgcn_mfma_f32_16x16x32_bf16(qf0[c], kf, sv0[n], 0, 0, 0);
        sv1[n] = __builtin_amdgcn_mfma_f32_16x16x32_bf16(qf1[c], kf, sv1[n], 0, 0, 0);
      }
    }
    __builtin_amdgcn_s_setprio(0);
#pragma unroll
    for (int j = 0; j < 4; j++) {
      int rbase = (fg * 4 + j) * 68;
#pragma unroll
      for (int n = 0; n < 4; n++) {
        float p0 = __builtin_amdgcn_exp2f(sv0[n][j]);
        float p1 = __builtin_amdgcn_exp2f(sv1[n][j]);
        unsigned pk = (__float_as_uint(p0) >> 16) | (__float_as_uint(p1) & 0xFFFF0000u);
        Pls2[w][rbase + fr + n * 16] = pk;
      }
    }
    __builtin_amdgcn_s_setprio(1);
#pragma unroll
    for (int c = 0; c < 2; c++) {
      const unsigned* pb = &Pls2[w][fr * 68 + c * 32 + fg * 8];
      uint4 qa = *(const uint4*)pb;
      uint4 qb = *(const uint4*)(pb + 4);
      uint4 u0, u1;
      u0.x = (qa.x & 0xFFFFu) | (qa.y << 16);
      u1.x = (qa.x >> 16) | (qa.y & 0xFFFF0000u);
      u0.y = (qa.z & 0xFFFFu) | (qa.w << 16);
      u1.y = (qa.z >> 16) | (qa.w & 0xFFFF0000u);
      u0.z = (qb.x & 0xFFFFu) | (qb.y << 16);
      u1.z = (qb.x >> 16) | (qb.y & 0xFFFF0000u);
      u0.w = (qb.z & 0xFFFFu) | (qb.w << 16);
      u1.w = (qb.z >> 16) | (qb.w & 0xFFFF0000u);
      bf16x8 pa0 = *(const bf16x8*)&u0;
      bf16x8 pa1 = *(const bf16x8*)&u1;
#pragma unroll
      for (int n = 0; n < 4; n++) {
        bf16x8 vb =
            *(const bf16x8*)&Vls[cur][(n * 16 + fr) * 64 + (((c * 4 + fg) ^ (fr & 7)) << 3)];
        accO0[n] = __builtin_amdgcn_mfma_f32_16x16x32_bf16(pa0, vb, accO0[n], 0, 0, 0);
        accO1[n] = __builtin_amdgcn_mfma_f32_16x16x32_bf16(pa1, vb, accO1[n], 0, 0, 0);
      }
      acc1_0 = __builtin_amdgcn_mfma_f32_16x16x32_bf16(pa0, ones, acc1_0, 0, 0, 0);
      acc1_1 = __builtin_amdgcn_mfma_f32_16x16x32_bf16(pa1, ones, acc1_1, 0, 0, 0);
    }
    __builtin_amdgcn_s_setprio(0);
    cur ^= 1;
  }
#pragma unroll
  for (int qs = 0; qs < 2; qs++) {
    const f32x4* accO = qs ? accO1 : accO0;
    const f32x4& acc1 = qs ? acc1_1 : acc1_0;
    float inv[4];
#pragma unroll
    for (int j = 0; j < 4; j++) inv[j] = 1.0f / acc1[j];
#pragma unroll
    for (int n = 0; n < 4; n++) {
#pragma unroll
      for (int j = 0; j < 4; j++) {
        float o = accO[n][j] * inv[j];
        int qrow = qp * 128 + qs * 64 + w * 16 + fg * 4 + j;
        int dh = fr + n * 16;
        attnb[(size_t)(b * L_ + qrow) * 1024 + (bh & 15) * 64 + dh] = f2bf(o);
      }
    }
  }
}

extern "C" void kernel_launch(void* const* d_in, const int* in_sizes, int n_in,
                              void* d_out, int out_size, void* d_ws, size_t ws_size,
                              hipStream_t stream) {
  const float* x = (const float*)d_in[0];
  const float* pos = (const float*)d_in[1];
  const float* pos_orig = (const float*)d_in[2];
  const float* timep = (const float*)d_in[3];
  const float* w_qkv = (const float*)d_in[4];
  const float* w_out = (const float*)d_in[5];
  const float* w_up = (const float*)d_in[6];
  const float* w_down = (const float*)d_in[7];
  const float* norm1 = (const float*)d_in[8];
  const float* norm2 = (const float*)d_in[9];
  const float* qk_scale = (const float*)d_in[10];
  float* out = (float*)d_out;
  char* ws = (char*)d_ws;
  size_t off = 0;
  auto alloc = [&](size_t bytes) {
    void* p = ws + off;
    off += bytes;
    return p;
  };
  ushort* xn = (ushort*)alloc(8ull << 20);
  ushort* qkvb = (ushort*)alloc(32ull << 20);   // qkv; out-proj partials; gelu out
  ushort* qrb = (ushort*)alloc(8ull << 20);     // q rot; down bf16 partial z=0
  ushort* krb = (ushort*)alloc(8ull << 20);     // k rot; partial z=1
  ushort* vTb = (ushort*)alloc(8ull << 20);     // vT;    partial z=2
  ushort* attnb = (ushort*)alloc(8ull << 20);   // attn;  partial z=3
  ushort* x1b = (ushort*)alloc(8ull << 20);     // bf16 residual x1
  ushort* wqkvb = (ushort*)alloc(6ull << 20);
  ushort* woutb = (ushort*)alloc(2ull << 20);
  ushort* wupb = (ushort*)alloc(8ull << 20);
  ushort* wdownb = (ushort*)alloc(8ull << 20);
  ushort* Pdown = qrb;   // 4 x 8MB bf16 down partials (qrb..attnb dead by then)
  ushort* Pout = qkvb;   // 4 x 8MB bf16 out-proj partials (qkvb dead after rope+vtrans)

  cast_all_kernel<<<12288, 256, 0, stream>>>(w_qkv, w_out, w_up, w_down,
                                             wqkvb, woutb, wupb, wdownb);

  rmsnorm_kernel<<<4096, 256, 0, stream>>>(x, norm1, xn);
  gemm256<0, 4, 2><<<dim3(16, 12), 512, 0, stream>>>(xn, wqkvb, qkvb, 4096, 3072, 1024, 1024);
  rope_kernel<<<16384, 256, 0, stream>>>(qkvb, pos, pos_orig, timep, qk_scale, qrb, krb);
  vtrans_kernel<<<dim3(32, 32), 256, 0, stream>>>(qkvb, vTb);
  attn_kernel<<<512, 256, 0, stream>>>(qrb, krb, vTb, attnb);
  // out-proj: 256^2 8-phase split-K=4 (grid 16x4x4 = 256 blocks), bf16 partials in qkvb
  gemm256<3, 4, 2><<<dim3(16, 4, 4), 512, 0, stream>>>(attnb, woutb, Pout, 4096, 1024, 1024, 256);
  // fused: x1 = x + sum(partials); x1b bf16; xn = rmsnorm(x1, norm2)
  reduce_out_rmsnorm_kernel<<<4096, 256, 0, stream>>>(Pout, x, norm2, x1b, xn);
  gemm256<2, 4, 2><<<dim3(16, 16), 512, 0, stream>>>(xn, wupb, qkvb, 4096, 4096, 1024, 1024);
  gemm256<3, 4, 2><<<dim3(16, 4, 4), 512, 0, stream>>>(qkvb, wdownb, Pdown, 4096, 1024, 4096, 1024);
  reduce_down4_kernel<<<4096, 256, 0, stream>>>(Pdown, x1b, out);
}

// Round 21
// 254.692 us; speedup vs baseline: 1.0147x; 1.0147x over previous
//
#include <hip/hip_runtime.h>

#define B_ 2
#define L_ 2048
#define D_ 1024
#define H_ 16
#define DH_ 64

typedef float f32x4 __attribute__((ext_vector_type(4)));
typedef __bf16 bf16x8 __attribute__((ext_vector_type(8)));

__device__ __forceinline__ ushort f2bf(float f) {
  unsigned u = __float_as_uint(f);
  u += 0x7fffu + ((u >> 16) & 1u);
  return (ushort)(u >> 16);
}
__device__ __forceinline__ float bf2f(ushort h) {
  return __uint_as_float(((unsigned)h) << 16);
}

__device__ __forceinline__ void gload_lds16(const void* g, void* l) {
  __builtin_amdgcn_global_load_lds(
      (const __attribute__((address_space(1))) unsigned*)g,
      (__attribute__((address_space(3))) unsigned*)l, 16, 0, 0);
}

__device__ __forceinline__ float gelu_f(float v) {
  return 0.5f * v * (1.0f + tanhf(0.7978845608f * (v + 0.044715f * v * v * v)));
}

// ---------------- cast f32 -> bf16, all four weights in one launch ----------------
__global__ __launch_bounds__(256) void cast_all_kernel(const float* __restrict__ w0,
                                                       const float* __restrict__ w1,
                                                       const float* __restrict__ w2,
                                                       const float* __restrict__ w3,
                                                       ushort* __restrict__ o0,
                                                       ushort* __restrict__ o1,
                                                       ushort* __restrict__ o2,
                                                       ushort* __restrict__ o3) {
  int i = blockIdx.x * 256 + threadIdx.x;
  const float* src;
  ushort* dst;
  int j = i;
  if (j < 786432) { src = w0; dst = o0; }
  else if (j < 786432 + 262144) { j -= 786432; src = w1; dst = o1; }
  else if (j < 786432 + 262144 + 1048576) { j -= 786432 + 262144; src = w2; dst = o2; }
  else { j -= 786432 + 262144 + 1048576; src = w3; dst = o3; }
  float4 v = ((const float4*)src)[j];
  ushort4 o;
  o.x = f2bf(v.x); o.y = f2bf(v.y); o.z = f2bf(v.z); o.w = f2bf(v.w);
  ((ushort4*)dst)[j] = o;
}

// ---------------- RMSNorm (T in, bf16 out), one block per row of 1024 ----------------
template <typename T>
__global__ __launch_bounds__(256) void rmsnorm_kernel(const T* __restrict__ x,
                                                      const float* __restrict__ scale,
                                                      ushort* __restrict__ out) {
  int row = blockIdx.x, t = threadIdx.x;
  float4 v;
  if constexpr (sizeof(T) == 4) {
    v = ((const float4*)((const float*)x + (size_t)row * D_))[t];
  } else {
    ushort4 u = ((const ushort4*)((const ushort*)x + (size_t)row * D_))[t];
    v.x = bf2f(u.x); v.y = bf2f(u.y); v.z = bf2f(u.z); v.w = bf2f(u.w);
  }
  float ss = v.x * v.x + v.y * v.y + v.z * v.z + v.w * v.w;
#pragma unroll
  for (int d = 1; d < 64; d <<= 1) ss += __shfl_xor(ss, d);
  __shared__ float wsum[4];
  if ((t & 63) == 0) wsum[t >> 6] = ss;
  __syncthreads();
  float tot = wsum[0] + wsum[1] + wsum[2] + wsum[3];
  float r = rsqrtf(tot * (1.0f / D_) + 1e-6f);
  float4 sc = ((const float4*)scale)[t];
  ushort4 o;
  o.x = f2bf(v.x * sc.x * r); o.y = f2bf(v.y * sc.y * r);
  o.z = f2bf(v.z * sc.z * r); o.w = f2bf(v.w * sc.w * r);
  ((ushort4*)(out + (size_t)row * D_))[t] = o;
}

// ============ 256x256 8-phase NT GEMM (m194-m201 template, plain HIP) ============
// Split-K via gridDim.z: block z covers K range [z*Klen,(z+1)*Klen).
// EPI 0: bf16 store. EPI 2: bf16 gelu. EPI 3: bf16 raw partial at z*M*N offset.
template <int EPI, int XR, int XC>
__global__ __launch_bounds__(512, 2) void gemm256(const ushort* __restrict__ A,
                                                  const ushort* __restrict__ Bw,
                                                  void* __restrict__ Cout,
                                                  int M, int N, int K, int Klen) {
  __shared__ __align__(16) ushort Als[2][2][128 * 64];
  __shared__ __align__(16) ushort Bls[2][2][128 * 64];
  const int tid = threadIdx.x;
  const int lane = tid & 63;
  const int w = tid >> 6;
  const int wm = w >> 2, wn = w & 3;
  const int fr = lane & 15, fg = lane >> 4;
  const int bid = blockIdx.y * gridDim.x + blockIdx.x;
  const int xcd = bid & 7, i0 = bid >> 3;
  const int CR = gridDim.x / XR, CC = gridDim.y / XC;
  const int rt = (xcd % XR) * CR + (i0 % CR);
  const int ct = (xcd / XR) * CC + (i0 / CR);
  const int row0 = rt * 256, col0 = ct * 256;
  const int koff = blockIdx.z * Klen;
  const ushort* Ab = A + (size_t)row0 * K + koff;
  const ushort* Bb = Bw + (size_t)col0 * K + koff;
  const int srow = tid >> 3;
  const int sxor = ((tid & 7) ^ (srow & 7)) * 8;

  f32x4 acc[8][4];
  f32x4 zero = {0.f, 0.f, 0.f, 0.f};
#pragma unroll
  for (int m = 0; m < 8; m++)
#pragma unroll
    for (int n = 0; n < 4; n++) acc[m][n] = zero;

  auto stageA = [&](int buf, int half, int kt) {
#pragma unroll
    for (int i = 0; i < 2; i++)
      gload_lds16(Ab + (size_t)(half * 128 + i * 64 + srow) * K + kt + sxor,
                  &Als[buf][half][i * 4096 + tid * 8]);
  };
  auto stageB = [&](int buf, int half, int kt) {
#pragma unroll
    for (int i = 0; i < 2; i++)
      gload_lds16(Bb + (size_t)(half * 128 + i * 64 + srow) * K + kt + sxor,
                  &Bls[buf][half][i * 4096 + tid * 8]);
  };
  const int nt = Klen >> 6;
  stageA(0, 0, 0); stageB(0, 0, 0); stageB(0, 1, 0); stageA(0, 1, 0);
  asm volatile("s_waitcnt vmcnt(0)" ::: "memory");
  __builtin_amdgcn_s_barrier();

  bf16x8 afr[4][2], b0[2][2], b1[2][2];
  for (int t = 0; t < nt; t++) {
    const int cur = t & 1, nxt = cur ^ 1;
    const int kn = (t + 1) << 6;
    const bool more = (t + 1 < nt);
    // phase 0: (0,0)
#pragma unroll
    for (int mf = 0; mf < 4; mf++)
#pragma unroll
      for (int ks = 0; ks < 2; ks++) {
        int r = wm * 64 + mf * 16 + fr;
        afr[mf][ks] = *(const bf16x8*)&Als[cur][0][r * 64 + (((ks * 4 + fg) ^ (r & 7)) << 3)];
      }
#pragma unroll
    for (int nf = 0; nf < 2; nf++)
#pragma unroll
      for (int ks = 0; ks < 2; ks++) {
        int c = wn * 32 + nf * 16 + fr;
        b0[nf][ks] = *(const bf16x8*)&Bls[cur][0][c * 64 + (((ks * 4 + fg) ^ (c & 7)) << 3)];
      }
    if (more) stageA(nxt, 0, kn);
    asm volatile("s_waitcnt vmcnt(4)" ::: "memory");
    __builtin_amdgcn_s_barrier();
    asm volatile("s_waitcnt lgkmcnt(0)" ::: "memory");
    __builtin_amdgcn_sched_barrier(0);
    __builtin_amdgcn_s_setprio(1);
#pragma unroll
    for (int mf = 0; mf < 4; mf++)
#pragma unroll
      for (int nf = 0; nf < 2; nf++)
#pragma unroll
        for (int ks = 0; ks < 2; ks++)
          acc[mf][nf] =
              __builtin_amdgcn_mfma_f32_16x16x32_bf16(afr[mf][ks], b0[nf][ks], acc[mf][nf], 0, 0, 0);
    __builtin_amdgcn_s_setprio(0);
    __builtin_amdgcn_s_barrier();
    // phase 1: (0,1)
#pragma unroll
    for (int nf = 0; nf < 2; nf++)
#pragma unroll
      for (int ks = 0; ks < 2; ks++) {
        int c = wn * 32 + nf * 16 + fr;
        b1[nf][ks] = *(const bf16x8*)&Bls[cur][1][c * 64 + (((ks * 4 + fg) ^ (c & 7)) << 3)];
      }
    if (more) stageB(nxt, 0, kn);
    asm volatile("s_waitcnt vmcnt(4)" ::: "memory");
    __builtin_amdgcn_s_barrier();
    asm volatile("s_waitcnt lgkmcnt(0)" ::: "memory");
    __builtin_amdgcn_sched_barrier(0);
    __builtin_amdgcn_s_setprio(1);
#pragma unroll
    for (int mf = 0; mf < 4; mf++)
#pragma unroll
      for (int nf = 0; nf < 2; nf++)
#pragma unroll
        for (int ks = 0; ks < 2; ks++)
          acc[mf][2 + nf] =
              __builtin_amdgcn_mfma_f32_16x16x32_bf16(afr[mf][ks], b1[nf][ks], acc[mf][2 + nf], 0, 0, 0);
    __builtin_amdgcn_s_setprio(0);
    __builtin_amdgcn_s_barrier();
    // phase 2: (1,1)
#pragma unroll
    for (int mf = 0; mf < 4; mf++)
#pragma unroll
      for (int ks = 0; ks < 2; ks++) {
        int r = wm * 64 + mf * 16 + fr;
        afr[mf][ks] = *(const bf16x8*)&Als[cur][1][r * 64 + (((ks * 4 + fg) ^ (r & 7)) << 3)];
      }
    if (more) stageB(nxt, 1, kn);
    asm volatile("s_waitcnt vmcnt(4)" ::: "memory");
    __builtin_amdgcn_s_barrier();
    asm volatile("s_waitcnt lgkmcnt(0)" ::: "memory");
    __builtin_amdgcn_sched_barrier(0);
    __builtin_amdgcn_s_setprio(1);
#pragma unroll
    for (int mf = 0; mf < 4; mf++)
#pragma unroll
      for (int nf = 0; nf < 2; nf++)
#pragma unroll
        for (int ks = 0; ks < 2; ks++)
          acc[4 + mf][2 + nf] =
              __builtin_amdgcn_mfma_f32_16x16x32_bf16(afr[mf][ks], b1[nf][ks], acc[4 + mf][2 + nf], 0, 0, 0);
    __builtin_amdgcn_s_setprio(0);
    __builtin_amdgcn_s_barrier();
    // phase 3: (1,0)
    if (more) stageA(nxt, 1, kn);
    asm volatile("s_waitcnt vmcnt(4)" ::: "memory");
    __builtin_amdgcn_s_barrier();
    asm volatile("s_waitcnt lgkmcnt(0)" ::: "memory");
    __builtin_amdgcn_sched_barrier(0);
    __builtin_amdgcn_s_setprio(1);
#pragma unroll
    for (int mf = 0; mf < 4; mf++)
#pragma unroll
      for (int nf = 0; nf < 2; nf++)
#pragma unroll
        for (int ks = 0; ks < 2; ks++)
          acc[4 + mf][nf] =
              __builtin_amdgcn_mfma_f32_16x16x32_bf16(afr[mf][ks], b0[nf][ks], acc[4 + mf][nf], 0, 0, 0);
    __builtin_amdgcn_s_setprio(0);
    __builtin_amdgcn_s_barrier();
  }
  const int orow = row0 + wm * 64 + fg * 4;
  const int ocol = col0 + wn * 32 + fr;
  ushort* Pz = (ushort*)Cout + (size_t)blockIdx.z * M * N;
#pragma unroll
  for (int am = 0; am < 8; am++) {
#pragma unroll
    for (int j = 0; j < 4; j++) {
      int r = orow + (am >> 2) * 128 + (am & 3) * 16 + j;
#pragma unroll
      for (int an = 0; an < 4; an++) {
        int cidx = ocol + (an >> 1) * 128 + (an & 1) * 16;
        size_t idx = (size_t)r * N + cidx;
        float v = acc[am][an][j];
        if (EPI == 0) {
          ((ushort*)Cout)[idx] = f2bf(v);
        } else if (EPI == 2) {
          ((ushort*)Cout)[idx] = f2bf(gelu_f(v));
        } else {
          Pz[idx] = f2bf(v);
        }
      }
    }
  }
}

// ---------------- 64x64 NT GEMM (ring structure) for out-proj ----------------
template <int EPI, int BM, int BN, int DEPTH, int XR, int XC, bool CTFAST>
__global__ __launch_bounds__(256) void gemm_nt(const ushort* __restrict__ A,
                                               const ushort* __restrict__ Bw,
                                               void* __restrict__ Cout,
                                               const void* __restrict__ resid,
                                               int M, int N, int K, int Klen) {
  constexpr int WROWS = BM / 2, WCOLS = BN / 2;
  constexpr int MR = WROWS / 16, NR = WCOLS / 16;
  constexpr int ALOADS = BM / 64, BLOADS = BN / 64;
  constexpr int NLOADS = ALOADS + BLOADS;
  __shared__ __align__(16) ushort Als[DEPTH][BM * 32];
  __shared__ __align__(16) ushort Bls[DEPTH][BN * 32];
  const int tid = threadIdx.x;
  const int lane = tid & 63;
  const int w = tid >> 6;
  const int wr = w >> 1, wc = w & 1;
  const int bid = blockIdx.y * gridDim.x + blockIdx.x;
  const int xcd = bid & 7;
  const int i0 = bid >> 3;
  const int CR = gridDim.x / XR, CC = gridDim.y / XC;
  int rt, ct;
  if constexpr (CTFAST) {
    rt = (xcd % XR) * CR + (i0 / CC);
    ct = (xcd / XR) * CC + (i0 % CC);
  } else {
    rt = (xcd % XR) * CR + (i0 % CR);
    ct = (xcd / XR) * CC + (i0 / CR);
  }
  const int row0 = rt * BM;
  const int col0 = ct * BN;
  const int koff = blockIdx.z * Klen;
  const ushort* Ab = A + (size_t)row0 * K + koff;
  const ushort* Bb = Bw + (size_t)col0 * K + koff;
  const int sr = tid >> 2;
  const int scA = (((tid & 3) ^ ((tid >> 3) & 3)) * 8);
  const int fr = lane & 15;
  const int fg = lane >> 4;
  f32x4 zero = {0.f, 0.f, 0.f, 0.f};
  f32x4 acc[MR][NR];
#pragma unroll
  for (int m = 0; m < MR; m++)
#pragma unroll
    for (int n = 0; n < NR; n++) acc[m][n] = zero;

  auto stage = [&](int slot, int kt) {
#pragma unroll
    for (int i2 = 0; i2 < ALOADS; i2++)
      gload_lds16(Ab + (size_t)(sr + 64 * i2) * K + kt + scA, &Als[slot][i2 * 2048 + tid * 8]);
#pragma unroll
    for (int i2 = 0; i2 < BLOADS; i2++)
      gload_lds16(Bb + (size_t)(sr + 64 * i2) * K + kt + scA, &Bls[slot][i2 * 2048 + tid * 8]);
  };
  const int nt = Klen >> 5;
#pragma unroll
  for (int p = 0; p < DEPTH - 1; p++) stage(p, p << 5);
  int cur = 0, sbuf = DEPTH - 1;
  for (int t = 0; t < nt; t++) {
    const int ahead = nt - 1 - t;
    if constexpr (DEPTH == 3) {
      if (ahead >= 1) asm volatile("s_waitcnt vmcnt(%0)" ::"i"(NLOADS) : "memory");
      else            asm volatile("s_waitcnt vmcnt(0)" ::: "memory");
    } else if constexpr (DEPTH == 4) {
      if (ahead >= 2)      asm volatile("s_waitcnt vmcnt(%0)" ::"i"(2 * NLOADS) : "memory");
      else if (ahead == 1) asm volatile("s_waitcnt vmcnt(%0)" ::"i"(NLOADS) : "memory");
      else                 asm volatile("s_waitcnt vmcnt(0)" ::: "memory");
    } else {
      if (ahead >= 3)      asm volatile("s_waitcnt vmcnt(%0)" ::"i"(3 * NLOADS) : "memory");
      else if (ahead == 2) asm volatile("s_waitcnt vmcnt(%0)" ::"i"(2 * NLOADS) : "memory");
      else if (ahead == 1) asm volatile("s_waitcnt vmcnt(%0)" ::"i"(NLOADS) : "memory");
      else                 asm volatile("s_waitcnt vmcnt(0)" ::: "memory");
    }
    __builtin_amdgcn_s_barrier();
    if (t + DEPTH - 1 < nt) {
      stage(sbuf, (t + DEPTH - 1) << 5);
      sbuf = (sbuf == DEPTH - 1) ? 0 : sbuf + 1;
    }
    bf16x8 af[MR], bfr[NR];
#pragma unroll
    for (int m = 0; m < MR; m++) {
      int rA = wr * WROWS + m * 16 + fr;
      af[m] = *(const bf16x8*)&Als[cur][rA * 32 + ((fg ^ ((rA >> 1) & 3)) << 3)];
    }
#pragma unroll
    for (int n = 0; n < NR; n++) {
      int rB = wc * WCOLS + n * 16 + fr;
      bfr[n] = *(const bf16x8*)&Bls[cur][rB * 32 + ((fg ^ ((rB >> 1) & 3)) << 3)];
    }
#pragma unroll
    for (int m = 0; m < MR; m++)
#pragma unroll
      for (int n = 0; n < NR; n++)
        acc[m][n] = __builtin_amdgcn_mfma_f32_16x16x32_bf16(af[m], bfr[n], acc[m][n], 0, 0, 0);
    cur = (cur == DEPTH - 1) ? 0 : cur + 1;
  }
  const int orow = row0 + wr * WROWS + fg * 4;
  const int ocol = col0 + wc * WCOLS + fr;
#pragma unroll
  for (int m = 0; m < MR; m++) {
#pragma unroll
    for (int j = 0; j < 4; j++) {
      int r = orow + m * 16 + j;
#pragma unroll
      for (int n = 0; n < NR; n++) {
        int cidx = ocol + n * 16;
        size_t idx = (size_t)r * N + cidx;
        float v = acc[m][n][j];
        if (EPI == 0) {
          ((ushort*)Cout)[idx] = f2bf(v);
        } else if (EPI == 1) {
          ((ushort*)Cout)[idx] = f2bf(((const float*)resid)[idx] + v);
        } else if (EPI == 2) {
          ((ushort*)Cout)[idx] = f2bf(gelu_f(v));
        }
      }
    }
  }
}

// ---------------- split-K=4 reduce: out = bf16resid + P0+P1+P2+P3 (bf16 partials) ------
__global__ __launch_bounds__(256) void reduce_down4_kernel(const ushort* __restrict__ P,
                                                           const ushort* __restrict__ residb,
                                                           float* __restrict__ out) {
  int i = blockIdx.x * 256 + threadIdx.x;
  ushort4 r = ((const ushort4*)residb)[i];
  float4 o;
  o.x = bf2f(r.x); o.y = bf2f(r.y); o.z = bf2f(r.z); o.w = bf2f(r.w);
#pragma unroll
  for (int z = 0; z < 4; z++) {
    ushort4 p = ((const ushort4*)(P + (size_t)z * 4194304))[i];
    o.x += bf2f(p.x); o.y += bf2f(p.y); o.z += bf2f(p.z); o.w += bf2f(p.w);
  }
  ((float4*)out)[i] = o;
}

// ---------------- RoPE + cosine-sim scaling; Q pre-scaled by log2(e) ----------------
__global__ __launch_bounds__(256) void rope_kernel(const ushort* __restrict__ qkv,
                                                   const float* __restrict__ pos,
                                                   const float* __restrict__ pos_orig,
                                                   const float* __restrict__ timep,
                                                   const float* __restrict__ qk_scale,
                                                   ushort* __restrict__ qr,
                                                   ushort* __restrict__ kr) {
  int gw = (blockIdx.x * 256 + threadIdx.x) >> 6;
  int lane = threadIdx.x & 63;
  int h = gw & 15;
  int row = gw >> 4;
  int b = row >> 11;
  int l = row & (L_ - 1);
  float qv = bf2f(qkv[(size_t)row * 3072 + h * 64 + lane]);
  float kv = bf2f(qkv[(size_t)row * 3072 + 1024 + h * 64 + lane]);
  float c = 1.0f, s = 0.0f;
  if (lane < 50) {
    int idx = lane < 25 ? lane : lane - 25;
    int sg = idx / 5, d = idx % 5;
    int fi = d * 16 + h;
    float th;
    if (sg == 4) {
      th = timep[row] * __expf(-(float)fi * 0.05756462732485115f);
    } else {
      float fr = 3.14159265358979323846f * __expf((float)fi * 0.028782313662425575f);
      const float* psrc = (sg == 0 || sg == 2) ? pos_orig : pos;
      int comp = (sg < 2) ? 1 : 0;
      th = (2.0f * psrc[(size_t)row * 2 + comp] - 1.0f) * fr;
    }
    s = sinf(th);
    c = cosf(th);
  }
  int partner = lane < 25 ? lane + 25 : lane - 25;
  float qp = __shfl(qv, partner, 64);
  float kp = __shfl(kv, partner, 64);
  float yq, yk;
  if (lane < 25) { yq = qv * c - qp * s; yk = kv * c - kp * s; }
  else if (lane < 50) { yq = qv * c + qp * s; yk = kv * c + kp * s; }
  else { yq = qv; yk = kv; }
  float sq = yq * yq, sk = yk * yk;
#pragma unroll
  for (int d = 1; d < 64; d <<= 1) { sq += __shfl_xor(sq, d); sk += __shfl_xor(sk, d); }
  float scl = sqrtf(qk_scale[h]);
  float qo = yq * (scl * 1.4426950408889634f) * rsqrtf(sq + 1e-6f);
  float ko = yk * scl * rsqrtf(sk + 1e-6f);
  size_t o = ((size_t)(b * 16 + h) * L_ + l) * 64 + lane;
  qr[o] = f2bf(qo);
  kr[o] = f2bf(ko);
}

// ---------------- V transpose ----------------
__global__ __launch_bounds__(256) void vtrans_kernel(const ushort* __restrict__ qkv,
                                                     ushort* __restrict__ vT) {
  __shared__ __align__(16) ushort tile[64][72];
  int t = threadIdx.x;
  int lt = blockIdx.x;
  int bh = blockIdx.y;
  int b = bh >> 4, h = bh & 15;
  int r = t >> 3, c0 = (t & 7) * 8;
#pragma unroll
  for (int half = 0; half < 2; half++) {
    const ushort* src =
        qkv + (size_t)(b * L_ + lt * 64 + r + half * 32) * 3072 + 2048 + h * 64 + c0;
    *(uint4*)&tile[r + half * 32][c0] = *(const uint4*)src;
  }
  __syncthreads();
#pragma unroll
  for (int half = 0; half < 2; half++) {
    int dh = r + half * 32;
    unsigned p0 = (unsigned)tile[c0 + 0][dh] | ((unsigned)tile[c0 + 1][dh] << 16);
    unsigned p1 = (unsigned)tile[c0 + 2][dh] | ((unsigned)tile[c0 + 3][dh] << 16);
    unsigned p2 = (unsigned)tile[c0 + 4][dh] | ((unsigned)tile[c0 + 5][dh] << 16);
    unsigned p3 = (unsigned)tile[c0 + 6][dh] | ((unsigned)tile[c0 + 7][dh] << 16);
    uint4 o; o.x = p0; o.y = p1; o.z = p2; o.w = p3;
    *(uint4*)&vT[((size_t)bh * 64 + dh) * L_ + lt * 64 + c0] = o;
  }
}

// ---------------- Flash attention: packed-P variant (R18 structure) -------------------
__global__ __launch_bounds__(256) void attn_kernel(const ushort* __restrict__ qr,
                                                   const ushort* __restrict__ kr,
                                                   const ushort* __restrict__ vT,
                                                   ushort* __restrict__ attnb) {
  __shared__ __align__(16) ushort Kls[2][64 * 64];
  __shared__ __align__(16) ushort Vls[2][64 * 64];
  __shared__ __align__(16) unsigned Pls2[4][16 * 68];
  const int tid = threadIdx.x, lane = tid & 63, w = tid >> 6;
  const int bid = blockIdx.x;
  const int qp = (bid >> 3) & 15;
  const int bh = (bid & 7) | ((bid >> 7) << 3);
  const int b = bh >> 4;
  const int fr = lane & 15, fg = lane >> 4;
  const ushort* Qb0 = qr + ((size_t)bh * L_ + qp * 128 + w * 16) * 64;
  const ushort* Qb1 = Qb0 + 64 * 64;
  bf16x8 qf0[2], qf1[2];
#pragma unroll
  for (int c = 0; c < 2; c++) {
    qf0[c] = *(const bf16x8*)(Qb0 + fr * 64 + c * 32 + fg * 8);
    qf1[c] = *(const bf16x8*)(Qb1 + fr * 64 + c * 32 + fg * 8);
  }
  const ushort ob[8] = {0x3F80, 0x3F80, 0x3F80, 0x3F80, 0x3F80, 0x3F80, 0x3F80, 0x3F80};
  const bf16x8 ones = *(const bf16x8*)ob;
  f32x4 zero = {0.f, 0.f, 0.f, 0.f};
  f32x4 accO0[4], accO1[4], acc1_0 = zero, acc1_1 = zero;
#pragma unroll
  for (int n = 0; n < 4; n++) { accO0[n] = zero; accO1[n] = zero; }
  const int sr = tid >> 3;
  const int scz = (((tid & 7) ^ (sr & 7)) * 8);
  auto stage = [&](int buf, int kt) {
    gload_lds16(kr + ((size_t)bh * L_ + kt + sr) * 64 + scz, &Kls[buf][tid * 8]);
    gload_lds16(kr + ((size_t)bh * L_ + kt + 32 + sr) * 64 + scz, &Kls[buf][2048 + tid * 8]);
    gload_lds16(vT + ((size_t)bh * 64 + sr) * L_ + kt + scz, &Vls[buf][tid * 8]);
    gload_lds16(vT + ((size_t)bh * 64 + 32 + sr) * L_ + kt + scz, &Vls[buf][2048 + tid * 8]);
  };
  stage(0, 0);
  int cur = 0;
  for (int t = 0; t < (L_ >> 6); t++) {
    asm volatile("s_waitcnt vmcnt(0)" ::: "memory");
    __builtin_amdgcn_s_barrier();
    __builtin_amdgcn_sched_barrier(0);
    if (t + 1 < (L_ >> 6)) stage(cur ^ 1, (t + 1) << 6);
    f32x4 sv0[4], sv1[4];
#pragma unroll
    for (int n = 0; n < 4; n++) { sv0[n] = zero; sv1[n] = zero; }
    __builtin_amdgcn_s_setprio(1);
#pragma unroll
    for (int c = 0; c < 2; c++) {
#pragma unroll
      for (int n = 0; n < 4; n++) {
        bf16x8 kf =
            *(const bf16x8*)&Kls[cur][(n * 16 + fr) * 64 + (((c * 4 + fg) ^ (fr & 7)) << 3)];
        sv0[n] = __builtin_amdgcn_mfma_f32_16x16x32_bf16(qf0[c], kf, sv0[n], 0, 0, 0);
        sv1[n] = __builtin_amdgcn_mfma_f32_16x16x32_bf16(qf1[c], kf, sv1[n], 0, 0, 0);
      }
    }
    __builtin_amdgcn_s_setprio(0);
#pragma unroll
    for (int j = 0; j < 4; j++) {
      int rbase = (fg * 4 + j) * 68;
#pragma unroll
      for (int n = 0; n < 4; n++) {
        float p0 = __builtin_amdgcn_exp2f(sv0[n][j]);
        float p1 = __builtin_amdgcn_exp2f(sv1[n][j]);
        unsigned pk = (__float_as_uint(p0) >> 16) | (__float_as_uint(p1) & 0xFFFF0000u);
        Pls2[w][rbase + fr + n * 16] = pk;
      }
    }
    __builtin_amdgcn_s_setprio(1);
#pragma unroll
    for (int c = 0; c < 2; c++) {
      const unsigned* pb = &Pls2[w][fr * 68 + c * 32 + fg * 8];
      uint4 qa = *(const uint4*)pb;
      uint4 qb = *(const uint4*)(pb + 4);
      uint4 u0, u1;
      u0.x = (qa.x & 0xFFFFu) | (qa.y << 16);
      u1.x = (qa.x >> 16) | (qa.y & 0xFFFF0000u);
      u0.y = (qa.z & 0xFFFFu) | (qa.w << 16);
      u1.y = (qa.z >> 16) | (qa.w & 0xFFFF0000u);
      u0.z = (qb.x & 0xFFFFu) | (qb.y << 16);
      u1.z = (qb.x >> 16) | (qb.y & 0xFFFF0000u);
      u0.w = (qb.z & 0xFFFFu) | (qb.w << 16);
      u1.w = (qb.z >> 16) | (qb.w & 0xFFFF0000u);
      bf16x8 pa0 = *(const bf16x8*)&u0;
      bf16x8 pa1 = *(const bf16x8*)&u1;
#pragma unroll
      for (int n = 0; n < 4; n++) {
        bf16x8 vb =
            *(const bf16x8*)&Vls[cur][(n * 16 + fr) * 64 + (((c * 4 + fg) ^ (fr & 7)) << 3)];
        accO0[n] = __builtin_amdgcn_mfma_f32_16x16x32_bf16(pa0, vb, accO0[n], 0, 0, 0);
        accO1[n] = __builtin_amdgcn_mfma_f32_16x16x32_bf16(pa1, vb, accO1[n], 0, 0, 0);
      }
      acc1_0 = __builtin_amdgcn_mfma_f32_16x16x32_bf16(pa0, ones, acc1_0, 0, 0, 0);
      acc1_1 = __builtin_amdgcn_mfma_f32_16x16x32_bf16(pa1, ones, acc1_1, 0, 0, 0);
    }
    __builtin_amdgcn_s_setprio(0);
    cur ^= 1;
  }
#pragma unroll
  for (int qs = 0; qs < 2; qs++) {
    const f32x4* accO = qs ? accO1 : accO0;
    const f32x4& acc1 = qs ? acc1_1 : acc1_0;
    float inv[4];
#pragma unroll
    for (int j = 0; j < 4; j++) inv[j] = 1.0f / acc1[j];
#pragma unroll
    for (int n = 0; n < 4; n++) {
#pragma unroll
      for (int j = 0; j < 4; j++) {
        float o = accO[n][j] * inv[j];
        int qrow = qp * 128 + qs * 64 + w * 16 + fg * 4 + j;
        int dh = fr + n * 16;
        attnb[(size_t)(b * L_ + qrow) * 1024 + (bh & 15) * 64 + dh] = f2bf(o);
      }
    }
  }
}

extern "C" void kernel_launch(void* const* d_in, const int* in_sizes, int n_in,
                              void* d_out, int out_size, void* d_ws, size_t ws_size,
                              hipStream_t stream) {
  const float* x = (const float*)d_in[0];
  const float* pos = (const float*)d_in[1];
  const float* pos_orig = (const float*)d_in[2];
  const float* timep = (const float*)d_in[3];
  const float* w_qkv = (const float*)d_in[4];
  const float* w_out = (const float*)d_in[5];
  const float* w_up = (const float*)d_in[6];
  const float* w_down = (const float*)d_in[7];
  const float* norm1 = (const float*)d_in[8];
  const float* norm2 = (const float*)d_in[9];
  const float* qk_scale = (const float*)d_in[10];
  float* out = (float*)d_out;
  char* ws = (char*)d_ws;
  size_t off = 0;
  auto alloc = [&](size_t bytes) {
    void* p = ws + off;
    off += bytes;
    return p;
  };
  ushort* xn = (ushort*)alloc(8ull << 20);
  ushort* qkvb = (ushort*)alloc(32ull << 20);   // qkv; gelu out (down A)
  ushort* qrb = (ushort*)alloc(8ull << 20);     // q rot; down bf16 partial z=0
  ushort* krb = (ushort*)alloc(8ull << 20);     // k rot; partial z=1
  ushort* vTb = (ushort*)alloc(8ull << 20);     // vT;    partial z=2
  ushort* attnb = (ushort*)alloc(8ull << 20);   // attn;  partial z=3
  ushort* x1b = (ushort*)alloc(8ull << 20);     // bf16 residual x1
  ushort* wqkvb = (ushort*)alloc(6ull << 20);
  ushort* woutb = (ushort*)alloc(2ull << 20);
  ushort* wupb = (ushort*)alloc(8ull << 20);
  ushort* wdownb = (ushort*)alloc(8ull << 20);
  ushort* Pdown = qrb;  // 4 x 8MB bf16 down partials (qrb..attnb dead by then)

  cast_all_kernel<<<12288, 256, 0, stream>>>(w_qkv, w_out, w_up, w_down,
                                             wqkvb, woutb, wupb, wdownb);

  rmsnorm_kernel<float><<<4096, 256, 0, stream>>>(x, norm1, xn);
  gemm256<0, 4, 2><<<dim3(16, 12), 512, 0, stream>>>(xn, wqkvb, qkvb, 4096, 3072, 1024, 1024);
  rope_kernel<<<16384, 256, 0, stream>>>(qkvb, pos, pos_orig, timep, qk_scale, qrb, krb);
  vtrans_kernel<<<dim3(32, 32), 256, 0, stream>>>(qkvb, vTb);
  attn_kernel<<<512, 256, 0, stream>>>(qrb, krb, vTb, attnb);
  gemm_nt<1, 64, 64, 5, 4, 2, false><<<dim3(64, 16), 256, 0, stream>>>(
      attnb, woutb, x1b, x, 4096, 1024, 1024, 1024);
  rmsnorm_kernel<ushort><<<4096, 256, 0, stream>>>(x1b, norm2, xn);
  gemm256<2, 4, 2><<<dim3(16, 16), 512, 0, stream>>>(xn, wupb, qkvb, 4096, 4096, 1024, 1024);
  gemm256<3, 4, 2><<<dim3(16, 4, 4), 512, 0, stream>>>(qkvb, wdownb, Pdown, 4096, 1024, 4096, 1024);
  reduce_down4_kernel<<<4096, 256, 0, stream>>>(Pdown, x1b, out);
}

// Round 22
// 252.824 us; speedup vs baseline: 1.0222x; 1.0074x over previous
//
#include <hip/hip_runtime.h>

#define B_ 2
#define L_ 2048
#define D_ 1024
#define H_ 16
#define DH_ 64

typedef float f32x4 __attribute__((ext_vector_type(4)));
typedef __bf16 bf16x8 __attribute__((ext_vector_type(8)));

__device__ __forceinline__ ushort f2bf(float f) {
  unsigned u = __float_as_uint(f);
  u += 0x7fffu + ((u >> 16) & 1u);
  return (ushort)(u >> 16);
}
__device__ __forceinline__ float bf2f(ushort h) {
  return __uint_as_float(((unsigned)h) << 16);
}

__device__ __forceinline__ void gload_lds16(const void* g, void* l) {
  __builtin_amdgcn_global_load_lds(
      (const __attribute__((address_space(1))) unsigned*)g,
      (__attribute__((address_space(3))) unsigned*)l, 16, 0, 0);
}

__device__ __forceinline__ float gelu_f(float v) {
  return 0.5f * v * (1.0f + tanhf(0.7978845608f * (v + 0.044715f * v * v * v)));
}

// ---------------- cast f32 -> bf16, all four weights in one launch ----------------
__global__ __launch_bounds__(256) void cast_all_kernel(const float* __restrict__ w0,
                                                       const float* __restrict__ w1,
                                                       const float* __restrict__ w2,
                                                       const float* __restrict__ w3,
                                                       ushort* __restrict__ o0,
                                                       ushort* __restrict__ o1,
                                                       ushort* __restrict__ o2,
                                                       ushort* __restrict__ o3) {
  int i = blockIdx.x * 256 + threadIdx.x;
  const float* src;
  ushort* dst;
  int j = i;
  if (j < 786432) { src = w0; dst = o0; }
  else if (j < 786432 + 262144) { j -= 786432; src = w1; dst = o1; }
  else if (j < 786432 + 262144 + 1048576) { j -= 786432 + 262144; src = w2; dst = o2; }
  else { j -= 786432 + 262144 + 1048576; src = w3; dst = o3; }
  float4 v = ((const float4*)src)[j];
  ushort4 o;
  o.x = f2bf(v.x); o.y = f2bf(v.y); o.z = f2bf(v.z); o.w = f2bf(v.w);
  ((ushort4*)dst)[j] = o;
}

// ---------------- RMSNorm (T in, bf16 out), one block per row of 1024 ----------------
template <typename T>
__global__ __launch_bounds__(256) void rmsnorm_kernel(const T* __restrict__ x,
                                                      const float* __restrict__ scale,
                                                      ushort* __restrict__ out) {
  int row = blockIdx.x, t = threadIdx.x;
  float4 v;
  if constexpr (sizeof(T) == 4) {
    v = ((const float4*)((const float*)x + (size_t)row * D_))[t];
  } else {
    ushort4 u = ((const ushort4*)((const ushort*)x + (size_t)row * D_))[t];
    v.x = bf2f(u.x); v.y = bf2f(u.y); v.z = bf2f(u.z); v.w = bf2f(u.w);
  }
  float ss = v.x * v.x + v.y * v.y + v.z * v.z + v.w * v.w;
#pragma unroll
  for (int d = 1; d < 64; d <<= 1) ss += __shfl_xor(ss, d);
  __shared__ float wsum[4];
  if ((t & 63) == 0) wsum[t >> 6] = ss;
  __syncthreads();
  float tot = wsum[0] + wsum[1] + wsum[2] + wsum[3];
  float r = rsqrtf(tot * (1.0f / D_) + 1e-6f);
  float4 sc = ((const float4*)scale)[t];
  ushort4 o;
  o.x = f2bf(v.x * sc.x * r); o.y = f2bf(v.y * sc.y * r);
  o.z = f2bf(v.z * sc.z * r); o.w = f2bf(v.w * sc.w * r);
  ((ushort4*)(out + (size_t)row * D_))[t] = o;
}

// ============ 256x256 8-phase NT GEMM (m194-m201 template, plain HIP) ============
// Split-K via gridDim.z: block z covers K range [z*Klen,(z+1)*Klen).
// EPI 0: bf16 store. EPI 2: bf16 gelu. EPI 3: bf16 raw partial at z*M*N offset.
template <int EPI, int XR, int XC>
__global__ __launch_bounds__(512, 2) void gemm256(const ushort* __restrict__ A,
                                                  const ushort* __restrict__ Bw,
                                                  void* __restrict__ Cout,
                                                  int M, int N, int K, int Klen) {
  __shared__ __align__(16) ushort Als[2][2][128 * 64];
  __shared__ __align__(16) ushort Bls[2][2][128 * 64];
  const int tid = threadIdx.x;
  const int lane = tid & 63;
  const int w = tid >> 6;
  const int wm = w >> 2, wn = w & 3;
  const int fr = lane & 15, fg = lane >> 4;
  const int bid = blockIdx.y * gridDim.x + blockIdx.x;
  const int xcd = bid & 7, i0 = bid >> 3;
  const int CR = gridDim.x / XR, CC = gridDim.y / XC;
  const int rt = (xcd % XR) * CR + (i0 % CR);
  const int ct = (xcd / XR) * CC + (i0 / CR);
  const int row0 = rt * 256, col0 = ct * 256;
  const int koff = blockIdx.z * Klen;
  const ushort* Ab = A + (size_t)row0 * K + koff;
  const ushort* Bb = Bw + (size_t)col0 * K + koff;
  const int srow = tid >> 3;
  const int sxor = ((tid & 7) ^ (srow & 7)) * 8;

  f32x4 acc[8][4];
  f32x4 zero = {0.f, 0.f, 0.f, 0.f};
#pragma unroll
  for (int m = 0; m < 8; m++)
#pragma unroll
    for (int n = 0; n < 4; n++) acc[m][n] = zero;

  auto stageA = [&](int buf, int half, int kt) {
#pragma unroll
    for (int i = 0; i < 2; i++)
      gload_lds16(Ab + (size_t)(half * 128 + i * 64 + srow) * K + kt + sxor,
                  &Als[buf][half][i * 4096 + tid * 8]);
  };
  auto stageB = [&](int buf, int half, int kt) {
#pragma unroll
    for (int i = 0; i < 2; i++)
      gload_lds16(Bb + (size_t)(half * 128 + i * 64 + srow) * K + kt + sxor,
                  &Bls[buf][half][i * 4096 + tid * 8]);
  };
  const int nt = Klen >> 6;
  stageA(0, 0, 0); stageB(0, 0, 0); stageB(0, 1, 0); stageA(0, 1, 0);
  asm volatile("s_waitcnt vmcnt(0)" ::: "memory");
  __builtin_amdgcn_s_barrier();

  bf16x8 afr[4][2], b0[2][2], b1[2][2];
  for (int t = 0; t < nt; t++) {
    const int cur = t & 1, nxt = cur ^ 1;
    const int kn = (t + 1) << 6;
    const bool more = (t + 1 < nt);
    // phase 0: (0,0)
#pragma unroll
    for (int mf = 0; mf < 4; mf++)
#pragma unroll
      for (int ks = 0; ks < 2; ks++) {
        int r = wm * 64 + mf * 16 + fr;
        afr[mf][ks] = *(const bf16x8*)&Als[cur][0][r * 64 + (((ks * 4 + fg) ^ (r & 7)) << 3)];
      }
#pragma unroll
    for (int nf = 0; nf < 2; nf++)
#pragma unroll
      for (int ks = 0; ks < 2; ks++) {
        int c = wn * 32 + nf * 16 + fr;
        b0[nf][ks] = *(const bf16x8*)&Bls[cur][0][c * 64 + (((ks * 4 + fg) ^ (c & 7)) << 3)];
      }
    if (more) stageA(nxt, 0, kn);
    asm volatile("s_waitcnt vmcnt(4)" ::: "memory");
    __builtin_amdgcn_s_barrier();
    asm volatile("s_waitcnt lgkmcnt(0)" ::: "memory");
    __builtin_amdgcn_sched_barrier(0);
    __builtin_amdgcn_s_setprio(1);
#pragma unroll
    for (int mf = 0; mf < 4; mf++)
#pragma unroll
      for (int nf = 0; nf < 2; nf++)
#pragma unroll
        for (int ks = 0; ks < 2; ks++)
          acc[mf][nf] =
              __builtin_amdgcn_mfma_f32_16x16x32_bf16(afr[mf][ks], b0[nf][ks], acc[mf][nf], 0, 0, 0);
    __builtin_amdgcn_s_setprio(0);
    __builtin_amdgcn_s_barrier();
    // phase 1: (0,1)
#pragma unroll
    for (int nf = 0; nf < 2; nf++)
#pragma unroll
      for (int ks = 0; ks < 2; ks++) {
        int c = wn * 32 + nf * 16 + fr;
        b1[nf][ks] = *(const bf16x8*)&Bls[cur][1][c * 64 + (((ks * 4 + fg) ^ (c & 7)) << 3)];
      }
    if (more) stageB(nxt, 0, kn);
    asm volatile("s_waitcnt vmcnt(4)" ::: "memory");
    __builtin_amdgcn_s_barrier();
    asm volatile("s_waitcnt lgkmcnt(0)" ::: "memory");
    __builtin_amdgcn_sched_barrier(0);
    __builtin_amdgcn_s_setprio(1);
#pragma unroll
    for (int mf = 0; mf < 4; mf++)
#pragma unroll
      for (int nf = 0; nf < 2; nf++)
#pragma unroll
        for (int ks = 0; ks < 2; ks++)
          acc[mf][2 + nf] =
              __builtin_amdgcn_mfma_f32_16x16x32_bf16(afr[mf][ks], b1[nf][ks], acc[mf][2 + nf], 0, 0, 0);
    __builtin_amdgcn_s_setprio(0);
    __builtin_amdgcn_s_barrier();
    // phase 2: (1,1)
#pragma unroll
    for (int mf = 0; mf < 4; mf++)
#pragma unroll
      for (int ks = 0; ks < 2; ks++) {
        int r = wm * 64 + mf * 16 + fr;
        afr[mf][ks] = *(const bf16x8*)&Als[cur][1][r * 64 + (((ks * 4 + fg) ^ (r & 7)) << 3)];
      }
    if (more) stageB(nxt, 1, kn);
    asm volatile("s_waitcnt vmcnt(4)" ::: "memory");
    __builtin_amdgcn_s_barrier();
    asm volatile("s_waitcnt lgkmcnt(0)" ::: "memory");
    __builtin_amdgcn_sched_barrier(0);
    __builtin_amdgcn_s_setprio(1);
#pragma unroll
    for (int mf = 0; mf < 4; mf++)
#pragma unroll
      for (int nf = 0; nf < 2; nf++)
#pragma unroll
        for (int ks = 0; ks < 2; ks++)
          acc[4 + mf][2 + nf] =
              __builtin_amdgcn_mfma_f32_16x16x32_bf16(afr[mf][ks], b1[nf][ks], acc[4 + mf][2 + nf], 0, 0, 0);
    __builtin_amdgcn_s_setprio(0);
    __builtin_amdgcn_s_barrier();
    // phase 3: (1,0)
    if (more) stageA(nxt, 1, kn);
    asm volatile("s_waitcnt vmcnt(4)" ::: "memory");
    __builtin_amdgcn_s_barrier();
    asm volatile("s_waitcnt lgkmcnt(0)" ::: "memory");
    __builtin_amdgcn_sched_barrier(0);
    __builtin_amdgcn_s_setprio(1);
#pragma unroll
    for (int mf = 0; mf < 4; mf++)
#pragma unroll
      for (int nf = 0; nf < 2; nf++)
#pragma unroll
        for (int ks = 0; ks < 2; ks++)
          acc[4 + mf][nf] =
              __builtin_amdgcn_mfma_f32_16x16x32_bf16(afr[mf][ks], b0[nf][ks], acc[4 + mf][nf], 0, 0, 0);
    __builtin_amdgcn_s_setprio(0);
    __builtin_amdgcn_s_barrier();
  }
  const int orow = row0 + wm * 64 + fg * 4;
  const int ocol = col0 + wn * 32 + fr;
  ushort* Pz = (ushort*)Cout + (size_t)blockIdx.z * M * N;
#pragma unroll
  for (int am = 0; am < 8; am++) {
#pragma unroll
    for (int j = 0; j < 4; j++) {
      int r = orow + (am >> 2) * 128 + (am & 3) * 16 + j;
#pragma unroll
      for (int an = 0; an < 4; an++) {
        int cidx = ocol + (an >> 1) * 128 + (an & 1) * 16;
        size_t idx = (size_t)r * N + cidx;
        float v = acc[am][an][j];
        if (EPI == 0) {
          ((ushort*)Cout)[idx] = f2bf(v);
        } else if (EPI == 2) {
          ((ushort*)Cout)[idx] = f2bf(gelu_f(v));
        } else {
          Pz[idx] = f2bf(v);
        }
      }
    }
  }
}

// ---------------- 64x64 NT GEMM (ring structure) for out-proj ----------------
template <int EPI, int BM, int BN, int DEPTH, int XR, int XC, bool CTFAST>
__global__ __launch_bounds__(256) void gemm_nt(const ushort* __restrict__ A,
                                               const ushort* __restrict__ Bw,
                                               void* __restrict__ Cout,
                                               const void* __restrict__ resid,
                                               int M, int N, int K, int Klen) {
  constexpr int WROWS = BM / 2, WCOLS = BN / 2;
  constexpr int MR = WROWS / 16, NR = WCOLS / 16;
  constexpr int ALOADS = BM / 64, BLOADS = BN / 64;
  constexpr int NLOADS = ALOADS + BLOADS;
  __shared__ __align__(16) ushort Als[DEPTH][BM * 32];
  __shared__ __align__(16) ushort Bls[DEPTH][BN * 32];
  const int tid = threadIdx.x;
  const int lane = tid & 63;
  const int w = tid >> 6;
  const int wr = w >> 1, wc = w & 1;
  const int bid = blockIdx.y * gridDim.x + blockIdx.x;
  const int xcd = bid & 7;
  const int i0 = bid >> 3;
  const int CR = gridDim.x / XR, CC = gridDim.y / XC;
  int rt, ct;
  if constexpr (CTFAST) {
    rt = (xcd % XR) * CR + (i0 / CC);
    ct = (xcd / XR) * CC + (i0 % CC);
  } else {
    rt = (xcd % XR) * CR + (i0 % CR);
    ct = (xcd / XR) * CC + (i0 / CR);
  }
  const int row0 = rt * BM;
  const int col0 = ct * BN;
  const int koff = blockIdx.z * Klen;
  const ushort* Ab = A + (size_t)row0 * K + koff;
  const ushort* Bb = Bw + (size_t)col0 * K + koff;
  const int sr = tid >> 2;
  const int scA = (((tid & 3) ^ ((tid >> 3) & 3)) * 8);
  const int fr = lane & 15;
  const int fg = lane >> 4;
  f32x4 zero = {0.f, 0.f, 0.f, 0.f};
  f32x4 acc[MR][NR];
#pragma unroll
  for (int m = 0; m < MR; m++)
#pragma unroll
    for (int n = 0; n < NR; n++) acc[m][n] = zero;

  auto stage = [&](int slot, int kt) {
#pragma unroll
    for (int i2 = 0; i2 < ALOADS; i2++)
      gload_lds16(Ab + (size_t)(sr + 64 * i2) * K + kt + scA, &Als[slot][i2 * 2048 + tid * 8]);
#pragma unroll
    for (int i2 = 0; i2 < BLOADS; i2++)
      gload_lds16(Bb + (size_t)(sr + 64 * i2) * K + kt + scA, &Bls[slot][i2 * 2048 + tid * 8]);
  };
  const int nt = Klen >> 5;
#pragma unroll
  for (int p = 0; p < DEPTH - 1; p++) stage(p, p << 5);
  int cur = 0, sbuf = DEPTH - 1;
  for (int t = 0; t < nt; t++) {
    const int ahead = nt - 1 - t;
    if constexpr (DEPTH == 3) {
      if (ahead >= 1) asm volatile("s_waitcnt vmcnt(%0)" ::"i"(NLOADS) : "memory");
      else            asm volatile("s_waitcnt vmcnt(0)" ::: "memory");
    } else if constexpr (DEPTH == 4) {
      if (ahead >= 2)      asm volatile("s_waitcnt vmcnt(%0)" ::"i"(2 * NLOADS) : "memory");
      else if (ahead == 1) asm volatile("s_waitcnt vmcnt(%0)" ::"i"(NLOADS) : "memory");
      else                 asm volatile("s_waitcnt vmcnt(0)" ::: "memory");
    } else {
      if (ahead >= 3)      asm volatile("s_waitcnt vmcnt(%0)" ::"i"(3 * NLOADS) : "memory");
      else if (ahead == 2) asm volatile("s_waitcnt vmcnt(%0)" ::"i"(2 * NLOADS) : "memory");
      else if (ahead == 1) asm volatile("s_waitcnt vmcnt(%0)" ::"i"(NLOADS) : "memory");
      else                 asm volatile("s_waitcnt vmcnt(0)" ::: "memory");
    }
    __builtin_amdgcn_s_barrier();
    if (t + DEPTH - 1 < nt) {
      stage(sbuf, (t + DEPTH - 1) << 5);
      sbuf = (sbuf == DEPTH - 1) ? 0 : sbuf + 1;
    }
    bf16x8 af[MR], bfr[NR];
#pragma unroll
    for (int m = 0; m < MR; m++) {
      int rA = wr * WROWS + m * 16 + fr;
      af[m] = *(const bf16x8*)&Als[cur][rA * 32 + ((fg ^ ((rA >> 1) & 3)) << 3)];
    }
#pragma unroll
    for (int n = 0; n < NR; n++) {
      int rB = wc * WCOLS + n * 16 + fr;
      bfr[n] = *(const bf16x8*)&Bls[cur][rB * 32 + ((fg ^ ((rB >> 1) & 3)) << 3)];
    }
#pragma unroll
    for (int m = 0; m < MR; m++)
#pragma unroll
      for (int n = 0; n < NR; n++)
        acc[m][n] = __builtin_amdgcn_mfma_f32_16x16x32_bf16(af[m], bfr[n], acc[m][n], 0, 0, 0);
    cur = (cur == DEPTH - 1) ? 0 : cur + 1;
  }
  const int orow = row0 + wr * WROWS + fg * 4;
  const int ocol = col0 + wc * WCOLS + fr;
#pragma unroll
  for (int m = 0; m < MR; m++) {
#pragma unroll
    for (int j = 0; j < 4; j++) {
      int r = orow + m * 16 + j;
#pragma unroll
      for (int n = 0; n < NR; n++) {
        int cidx = ocol + n * 16;
        size_t idx = (size_t)r * N + cidx;
        float v = acc[m][n][j];
        if (EPI == 0) {
          ((ushort*)Cout)[idx] = f2bf(v);
        } else if (EPI == 1) {
          ((ushort*)Cout)[idx] = f2bf(((const float*)resid)[idx] + v);
        } else if (EPI == 2) {
          ((ushort*)Cout)[idx] = f2bf(gelu_f(v));
        }
      }
    }
  }
}

// ---------------- split-K=4 reduce: out = bf16resid + P0+P1+P2+P3 (bf16 partials) ------
__global__ __launch_bounds__(256) void reduce_down4_kernel(const ushort* __restrict__ P,
                                                           const ushort* __restrict__ residb,
                                                           float* __restrict__ out) {
  int i = blockIdx.x * 256 + threadIdx.x;
  ushort4 r = ((const ushort4*)residb)[i];
  float4 o;
  o.x = bf2f(r.x); o.y = bf2f(r.y); o.z = bf2f(r.z); o.w = bf2f(r.w);
#pragma unroll
  for (int z = 0; z < 4; z++) {
    ushort4 p = ((const ushort4*)(P + (size_t)z * 4194304))[i];
    o.x += bf2f(p.x); o.y += bf2f(p.y); o.z += bf2f(p.z); o.w += bf2f(p.w);
  }
  ((float4*)out)[i] = o;
}

// ---------------- RoPE + cosine-sim scaling; Q pre-scaled by log2(e) ----------------
__global__ __launch_bounds__(256) void rope_kernel(const ushort* __restrict__ qkv,
                                                   const float* __restrict__ pos,
                                                   const float* __restrict__ pos_orig,
                                                   const float* __restrict__ timep,
                                                   const float* __restrict__ qk_scale,
                                                   ushort* __restrict__ qr,
                                                   ushort* __restrict__ kr) {
  int gw = (blockIdx.x * 256 + threadIdx.x) >> 6;
  int lane = threadIdx.x & 63;
  int h = gw & 15;
  int row = gw >> 4;
  int b = row >> 11;
  int l = row & (L_ - 1);
  float qv = bf2f(qkv[(size_t)row * 3072 + h * 64 + lane]);
  float kv = bf2f(qkv[(size_t)row * 3072 + 1024 + h * 64 + lane]);
  float c = 1.0f, s = 0.0f;
  if (lane < 50) {
    int idx = lane < 25 ? lane : lane - 25;
    int sg = idx / 5, d = idx % 5;
    int fi = d * 16 + h;
    float th;
    if (sg == 4) {
      th = timep[row] * __expf(-(float)fi * 0.05756462732485115f);
    } else {
      float fr = 3.14159265358979323846f * __expf((float)fi * 0.028782313662425575f);
      const float* psrc = (sg == 0 || sg == 2) ? pos_orig : pos;
      int comp = (sg < 2) ? 1 : 0;
      th = (2.0f * psrc[(size_t)row * 2 + comp] - 1.0f) * fr;
    }
    s = sinf(th);
    c = cosf(th);
  }
  int partner = lane < 25 ? lane + 25 : lane - 25;
  float qp = __shfl(qv, partner, 64);
  float kp = __shfl(kv, partner, 64);
  float yq, yk;
  if (lane < 25) { yq = qv * c - qp * s; yk = kv * c - kp * s; }
  else if (lane < 50) { yq = qv * c + qp * s; yk = kv * c + kp * s; }
  else { yq = qv; yk = kv; }
  float sq = yq * yq, sk = yk * yk;
#pragma unroll
  for (int d = 1; d < 64; d <<= 1) { sq += __shfl_xor(sq, d); sk += __shfl_xor(sk, d); }
  float scl = sqrtf(qk_scale[h]);
  float qo = yq * (scl * 1.4426950408889634f) * rsqrtf(sq + 1e-6f);
  float ko = yk * scl * rsqrtf(sk + 1e-6f);
  size_t o = ((size_t)(b * 16 + h) * L_ + l) * 64 + lane;
  qr[o] = f2bf(qo);
  kr[o] = f2bf(ko);
}

// ---------------- V transpose ----------------
__global__ __launch_bounds__(256) void vtrans_kernel(const ushort* __restrict__ qkv,
                                                     ushort* __restrict__ vT) {
  __shared__ __align__(16) ushort tile[64][72];
  int t = threadIdx.x;
  int lt = blockIdx.x;
  int bh = blockIdx.y;
  int b = bh >> 4, h = bh & 15;
  int r = t >> 3, c0 = (t & 7) * 8;
#pragma unroll
  for (int half = 0; half < 2; half++) {
    const ushort* src =
        qkv + (size_t)(b * L_ + lt * 64 + r + half * 32) * 3072 + 2048 + h * 64 + c0;
    *(uint4*)&tile[r + half * 32][c0] = *(const uint4*)src;
  }
  __syncthreads();
#pragma unroll
  for (int half = 0; half < 2; half++) {
    int dh = r + half * 32;
    unsigned p0 = (unsigned)tile[c0 + 0][dh] | ((unsigned)tile[c0 + 1][dh] << 16);
    unsigned p1 = (unsigned)tile[c0 + 2][dh] | ((unsigned)tile[c0 + 3][dh] << 16);
    unsigned p2 = (unsigned)tile[c0 + 4][dh] | ((unsigned)tile[c0 + 5][dh] << 16);
    unsigned p3 = (unsigned)tile[c0 + 6][dh] | ((unsigned)tile[c0 + 7][dh] << 16);
    uint4 o; o.x = p0; o.y = p1; o.z = p2; o.w = p3;
    *(uint4*)&vT[((size_t)bh * 64 + dh) * L_ + lt * 64 + c0] = o;
  }
}

// ---------------- Flash attention: packed-P with v_perm pack/unpack -------------------
// Pack/unpack of the two q-sets' P values now use v_perm_b32 (1 inst each vs shr/and/or
// triples): pk = perm(p1,p0,0x07060302); unpack lo = perm(hiWord,loWord,0x05040100),
// hi = perm(hiWord,loWord,0x07060302). ~64 fewer VALU ops per lane per tile.
__global__ __launch_bounds__(256) void attn_kernel(const ushort* __restrict__ qr,
                                                   const ushort* __restrict__ kr,
                                                   const ushort* __restrict__ vT,
                                                   ushort* __restrict__ attnb) {
  __shared__ __align__(16) ushort Kls[2][64 * 64];
  __shared__ __align__(16) ushort Vls[2][64 * 64];
  __shared__ __align__(16) unsigned Pls2[4][16 * 68];
  const int tid = threadIdx.x, lane = tid & 63, w = tid >> 6;
  const int bid = blockIdx.x;
  const int qp = (bid >> 3) & 15;
  const int bh = (bid & 7) | ((bid >> 7) << 3);
  const int b = bh >> 4;
  const int fr = lane & 15, fg = lane >> 4;
  const ushort* Qb0 = qr + ((size_t)bh * L_ + qp * 128 + w * 16) * 64;
  const ushort* Qb1 = Qb0 + 64 * 64;
  bf16x8 qf0[2], qf1[2];
#pragma unroll
  for (int c = 0; c < 2; c++) {
    qf0[c] = *(const bf16x8*)(Qb0 + fr * 64 + c * 32 + fg * 8);
    qf1[c] = *(const bf16x8*)(Qb1 + fr * 64 + c * 32 + fg * 8);
  }
  const ushort ob[8] = {0x3F80, 0x3F80, 0x3F80, 0x3F80, 0x3F80, 0x3F80, 0x3F80, 0x3F80};
  const bf16x8 ones = *(const bf16x8*)ob;
  f32x4 zero = {0.f, 0.f, 0.f, 0.f};
  f32x4 accO0[4], accO1[4], acc1_0 = zero, acc1_1 = zero;
#pragma unroll
  for (int n = 0; n < 4; n++) { accO0[n] = zero; accO1[n] = zero; }
  const int sr = tid >> 3;
  const int scz = (((tid & 7) ^ (sr & 7)) * 8);
  auto stage = [&](int buf, int kt) {
    gload_lds16(kr + ((size_t)bh * L_ + kt + sr) * 64 + scz, &Kls[buf][tid * 8]);
    gload_lds16(kr + ((size_t)bh * L_ + kt + 32 + sr) * 64 + scz, &Kls[buf][2048 + tid * 8]);
    gload_lds16(vT + ((size_t)bh * 64 + sr) * L_ + kt + scz, &Vls[buf][tid * 8]);
    gload_lds16(vT + ((size_t)bh * 64 + 32 + sr) * L_ + kt + scz, &Vls[buf][2048 + tid * 8]);
  };
  stage(0, 0);
  int cur = 0;
  for (int t = 0; t < (L_ >> 6); t++) {
    asm volatile("s_waitcnt vmcnt(0)" ::: "memory");
    __builtin_amdgcn_s_barrier();
    __builtin_amdgcn_sched_barrier(0);
    if (t + 1 < (L_ >> 6)) stage(cur ^ 1, (t + 1) << 6);
    f32x4 sv0[4], sv1[4];
#pragma unroll
    for (int n = 0; n < 4; n++) { sv0[n] = zero; sv1[n] = zero; }
    __builtin_amdgcn_s_setprio(1);
#pragma unroll
    for (int c = 0; c < 2; c++) {
#pragma unroll
      for (int n = 0; n < 4; n++) {
        bf16x8 kf =
            *(const bf16x8*)&Kls[cur][(n * 16 + fr) * 64 + (((c * 4 + fg) ^ (fr & 7)) << 3)];
        sv0[n] = __builtin_amdgcn_mfma_f32_16x16x32_bf16(qf0[c], kf, sv0[n], 0, 0, 0);
        sv1[n] = __builtin_amdgcn_mfma_f32_16x16x32_bf16(qf1[c], kf, sv1[n], 0, 0, 0);
      }
    }
    __builtin_amdgcn_s_setprio(0);
    // p = exp2(sv); pack qs0(lo)/qs1(hi) via v_perm (1 inst)
#pragma unroll
    for (int j = 0; j < 4; j++) {
      int rbase = (fg * 4 + j) * 68;
#pragma unroll
      for (int n = 0; n < 4; n++) {
        float p0 = __builtin_amdgcn_exp2f(sv0[n][j]);
        float p1 = __builtin_amdgcn_exp2f(sv1[n][j]);
        unsigned pk = __builtin_amdgcn_perm(__float_as_uint(p1), __float_as_uint(p0),
                                            0x07060302u);
        Pls2[w][rbase + fr + n * 16] = pk;
      }
    }
    __builtin_amdgcn_s_setprio(1);
#pragma unroll
    for (int c = 0; c < 2; c++) {
      const unsigned* pb = &Pls2[w][fr * 68 + c * 32 + fg * 8];
      uint4 qa = *(const uint4*)pb;
      uint4 qb = *(const uint4*)(pb + 4);
      uint4 u0, u1;
      u0.x = __builtin_amdgcn_perm(qa.y, qa.x, 0x05040100u);
      u1.x = __builtin_amdgcn_perm(qa.y, qa.x, 0x07060302u);
      u0.y = __builtin_amdgcn_perm(qa.w, qa.z, 0x05040100u);
      u1.y = __builtin_amdgcn_perm(qa.w, qa.z, 0x07060302u);
      u0.z = __builtin_amdgcn_perm(qb.y, qb.x, 0x05040100u);
      u1.z = __builtin_amdgcn_perm(qb.y, qb.x, 0x07060302u);
      u0.w = __builtin_amdgcn_perm(qb.w, qb.z, 0x05040100u);
      u1.w = __builtin_amdgcn_perm(qb.w, qb.z, 0x07060302u);
      bf16x8 pa0 = *(const bf16x8*)&u0;
      bf16x8 pa1 = *(const bf16x8*)&u1;
#pragma unroll
      for (int n = 0; n < 4; n++) {
        bf16x8 vb =
            *(const bf16x8*)&Vls[cur][(n * 16 + fr) * 64 + (((c * 4 + fg) ^ (fr & 7)) << 3)];
        accO0[n] = __builtin_amdgcn_mfma_f32_16x16x32_bf16(pa0, vb, accO0[n], 0, 0, 0);
        accO1[n] = __builtin_amdgcn_mfma_f32_16x16x32_bf16(pa1, vb, accO1[n], 0, 0, 0);
      }
      acc1_0 = __builtin_amdgcn_mfma_f32_16x16x32_bf16(pa0, ones, acc1_0, 0, 0, 0);
      acc1_1 = __builtin_amdgcn_mfma_f32_16x16x32_bf16(pa1, ones, acc1_1, 0, 0, 0);
    }
    __builtin_amdgcn_s_setprio(0);
    cur ^= 1;
  }
#pragma unroll
  for (int qs = 0; qs < 2; qs++) {
    const f32x4* accO = qs ? accO1 : accO0;
    const f32x4& acc1 = qs ? acc1_1 : acc1_0;
    float inv[4];
#pragma unroll
    for (int j = 0; j < 4; j++) inv[j] = 1.0f / acc1[j];
#pragma unroll
    for (int n = 0; n < 4; n++) {
#pragma unroll
      for (int j = 0; j < 4; j++) {
        float o = accO[n][j] * inv[j];
        int qrow = qp * 128 + qs * 64 + w * 16 + fg * 4 + j;
        int dh = fr + n * 16;
        attnb[(size_t)(b * L_ + qrow) * 1024 + (bh & 15) * 64 + dh] = f2bf(o);
      }
    }
  }
}

extern "C" void kernel_launch(void* const* d_in, const int* in_sizes, int n_in,
                              void* d_out, int out_size, void* d_ws, size_t ws_size,
                              hipStream_t stream) {
  const float* x = (const float*)d_in[0];
  const float* pos = (const float*)d_in[1];
  const float* pos_orig = (const float*)d_in[2];
  const float* timep = (const float*)d_in[3];
  const float* w_qkv = (const float*)d_in[4];
  const float* w_out = (const float*)d_in[5];
  const float* w_up = (const float*)d_in[6];
  const float* w_down = (const float*)d_in[7];
  const float* norm1 = (const float*)d_in[8];
  const float* norm2 = (const float*)d_in[9];
  const float* qk_scale = (const float*)d_in[10];
  float* out = (float*)d_out;
  char* ws = (char*)d_ws;
  size_t off = 0;
  auto alloc = [&](size_t bytes) {
    void* p = ws + off;
    off += bytes;
    return p;
  };
  ushort* xn = (ushort*)alloc(8ull << 20);
  ushort* qkvb = (ushort*)alloc(32ull << 20);   // qkv; gelu out (down A)
  ushort* qrb = (ushort*)alloc(8ull << 20);     // q rot; down bf16 partial z=0
  ushort* krb = (ushort*)alloc(8ull << 20);     // k rot; partial z=1
  ushort* vTb = (ushort*)alloc(8ull << 20);     // vT;    partial z=2
  ushort* attnb = (ushort*)alloc(8ull << 20);   // attn;  partial z=3
  ushort* x1b = (ushort*)alloc(8ull << 20);     // bf16 residual x1
  ushort* wqkvb = (ushort*)alloc(6ull << 20);
  ushort* woutb = (ushort*)alloc(2ull << 20);
  ushort* wupb = (ushort*)alloc(8ull << 20);
  ushort* wdownb = (ushort*)alloc(8ull << 20);
  ushort* Pdown = qrb;  // 4 x 8MB bf16 down partials (qrb..attnb dead by then)

  cast_all_kernel<<<12288, 256, 0, stream>>>(w_qkv, w_out, w_up, w_down,
                                             wqkvb, woutb, wupb, wdownb);

  rmsnorm_kernel<float><<<4096, 256, 0, stream>>>(x, norm1, xn);
  gemm256<0, 4, 2><<<dim3(16, 12), 512, 0, stream>>>(xn, wqkvb, qkvb, 4096, 3072, 1024, 1024);
  rope_kernel<<<16384, 256, 0, stream>>>(qkvb, pos, pos_orig, timep, qk_scale, qrb, krb);
  vtrans_kernel<<<dim3(32, 32), 256, 0, stream>>>(qkvb, vTb);
  attn_kernel<<<512, 256, 0, stream>>>(qrb, krb, vTb, attnb);
  gemm_nt<1, 64, 64, 5, 4, 2, false><<<dim3(64, 16), 256, 0, stream>>>(
      attnb, woutb, x1b, x, 4096, 1024, 1024, 1024);
  rmsnorm_kernel<ushort><<<4096, 256, 0, stream>>>(x1b, norm2, xn);
  gemm256<2, 4, 2><<<dim3(16, 16), 512, 0, stream>>>(xn, wupb, qkvb, 4096, 4096, 1024, 1024);
  gemm256<3, 4, 2><<<dim3(16, 4, 4), 512, 0, stream>>>(qkvb, wdownb, Pdown, 4096, 1024, 4096, 1024);
  reduce_down4_kernel<<<4096, 256, 0, stream>>>(Pdown, x1b, out);
}

// Round 23
// 243.178 us; speedup vs baseline: 1.0628x; 1.0397x over previous
//
#include <hip/hip_runtime.h>

#define B_ 2
#define L_ 2048
#define D_ 1024
#define H_ 16
#define DH_ 64

typedef float f32x4 __attribute__((ext_vector_type(4)));
typedef __bf16 bf16x8 __attribute__((ext_vector_type(8)));

__device__ __forceinline__ ushort f2bf(float f) {
  unsigned u = __float_as_uint(f);
  u += 0x7fffu + ((u >> 16) & 1u);
  return (ushort)(u >> 16);
}
__device__ __forceinline__ float bf2f(ushort h) {
  return __uint_as_float(((unsigned)h) << 16);
}

__device__ __forceinline__ void gload_lds16(const void* g, void* l) {
  __builtin_amdgcn_global_load_lds(
      (const __attribute__((address_space(1))) unsigned*)g,
      (__attribute__((address_space(3))) unsigned*)l, 16, 0, 0);
}

// gelu(v) = 0.5 v (1 + tanh(u)), u = 0.79788456(v + 0.044715 v^3)
//         = v * sigmoid(2u) = v / (1 + exp2(-2u*log2e))   [exp2+rcp, ~5 ops vs libm tanhf]
__device__ __forceinline__ float gelu_f(float v) {
  float u = 0.7978845608f * (v + 0.044715f * v * v * v);
  float e = __builtin_amdgcn_exp2f(u * -2.885390081777927f);  // -2*log2(e)*u
  return v * __builtin_amdgcn_rcpf(1.0f + e);
}

// ---------------- cast f32 -> bf16, all four weights in one launch ----------------
__global__ __launch_bounds__(256) void cast_all_kernel(const float* __restrict__ w0,
                                                       const float* __restrict__ w1,
                                                       const float* __restrict__ w2,
                                                       const float* __restrict__ w3,
                                                       ushort* __restrict__ o0,
                                                       ushort* __restrict__ o1,
                                                       ushort* __restrict__ o2,
                                                       ushort* __restrict__ o3) {
  int i = blockIdx.x * 256 + threadIdx.x;
  const float* src;
  ushort* dst;
  int j = i;
  if (j < 786432) { src = w0; dst = o0; }
  else if (j < 786432 + 262144) { j -= 786432; src = w1; dst = o1; }
  else if (j < 786432 + 262144 + 1048576) { j -= 786432 + 262144; src = w2; dst = o2; }
  else { j -= 786432 + 262144 + 1048576; src = w3; dst = o3; }
  float4 v = ((const float4*)src)[j];
  ushort4 o;
  o.x = f2bf(v.x); o.y = f2bf(v.y); o.z = f2bf(v.z); o.w = f2bf(v.w);
  ((ushort4*)dst)[j] = o;
}

// ---------------- RMSNorm (T in, bf16 out), one block per row of 1024 ----------------
template <typename T>
__global__ __launch_bounds__(256) void rmsnorm_kernel(const T* __restrict__ x,
                                                      const float* __restrict__ scale,
                                                      ushort* __restrict__ out) {
  int row = blockIdx.x, t = threadIdx.x;
  float4 v;
  if constexpr (sizeof(T) == 4) {
    v = ((const float4*)((const float*)x + (size_t)row * D_))[t];
  } else {
    ushort4 u = ((const ushort4*)((const ushort*)x + (size_t)row * D_))[t];
    v.x = bf2f(u.x); v.y = bf2f(u.y); v.z = bf2f(u.z); v.w = bf2f(u.w);
  }
  float ss = v.x * v.x + v.y * v.y + v.z * v.z + v.w * v.w;
#pragma unroll
  for (int d = 1; d < 64; d <<= 1) ss += __shfl_xor(ss, d);
  __shared__ float wsum[4];
  if ((t & 63) == 0) wsum[t >> 6] = ss;
  __syncthreads();
  float tot = wsum[0] + wsum[1] + wsum[2] + wsum[3];
  float r = rsqrtf(tot * (1.0f / D_) + 1e-6f);
  float4 sc = ((const float4*)scale)[t];
  ushort4 o;
  o.x = f2bf(v.x * sc.x * r); o.y = f2bf(v.y * sc.y * r);
  o.z = f2bf(v.z * sc.z * r); o.w = f2bf(v.w * sc.w * r);
  ((ushort4*)(out + (size_t)row * D_))[t] = o;
}

// ============ 256x256 8-phase NT GEMM (m194-m201 template, plain HIP) ============
// Split-K via gridDim.z: block z covers K range [z*Klen,(z+1)*Klen).
// EPI 0: bf16 store. EPI 2: bf16 gelu. EPI 3: bf16 raw partial at z*M*N offset.
template <int EPI, int XR, int XC>
__global__ __launch_bounds__(512, 2) void gemm256(const ushort* __restrict__ A,
                                                  const ushort* __restrict__ Bw,
                                                  void* __restrict__ Cout,
                                                  int M, int N, int K, int Klen) {
  __shared__ __align__(16) ushort Als[2][2][128 * 64];
  __shared__ __align__(16) ushort Bls[2][2][128 * 64];
  const int tid = threadIdx.x;
  const int lane = tid & 63;
  const int w = tid >> 6;
  const int wm = w >> 2, wn = w & 3;
  const int fr = lane & 15, fg = lane >> 4;
  const int bid = blockIdx.y * gridDim.x + blockIdx.x;
  const int xcd = bid & 7, i0 = bid >> 3;
  const int CR = gridDim.x / XR, CC = gridDim.y / XC;
  const int rt = (xcd % XR) * CR + (i0 % CR);
  const int ct = (xcd / XR) * CC + (i0 / CR);
  const int row0 = rt * 256, col0 = ct * 256;
  const int koff = blockIdx.z * Klen;
  const ushort* Ab = A + (size_t)row0 * K + koff;
  const ushort* Bb = Bw + (size_t)col0 * K + koff;
  const int srow = tid >> 3;
  const int sxor = ((tid & 7) ^ (srow & 7)) * 8;

  f32x4 acc[8][4];
  f32x4 zero = {0.f, 0.f, 0.f, 0.f};
#pragma unroll
  for (int m = 0; m < 8; m++)
#pragma unroll
    for (int n = 0; n < 4; n++) acc[m][n] = zero;

  auto stageA = [&](int buf, int half, int kt) {
#pragma unroll
    for (int i = 0; i < 2; i++)
      gload_lds16(Ab + (size_t)(half * 128 + i * 64 + srow) * K + kt + sxor,
                  &Als[buf][half][i * 4096 + tid * 8]);
  };
  auto stageB = [&](int buf, int half, int kt) {
#pragma unroll
    for (int i = 0; i < 2; i++)
      gload_lds16(Bb + (size_t)(half * 128 + i * 64 + srow) * K + kt + sxor,
                  &Bls[buf][half][i * 4096 + tid * 8]);
  };
  const int nt = Klen >> 6;
  stageA(0, 0, 0); stageB(0, 0, 0); stageB(0, 1, 0); stageA(0, 1, 0);
  asm volatile("s_waitcnt vmcnt(0)" ::: "memory");
  __builtin_amdgcn_s_barrier();

  bf16x8 afr[4][2], b0[2][2], b1[2][2];
  for (int t = 0; t < nt; t++) {
    const int cur = t & 1, nxt = cur ^ 1;
    const int kn = (t + 1) << 6;
    const bool more = (t + 1 < nt);
    // phase 0: (0,0)
#pragma unroll
    for (int mf = 0; mf < 4; mf++)
#pragma unroll
      for (int ks = 0; ks < 2; ks++) {
        int r = wm * 64 + mf * 16 + fr;
        afr[mf][ks] = *(const bf16x8*)&Als[cur][0][r * 64 + (((ks * 4 + fg) ^ (r & 7)) << 3)];
      }
#pragma unroll
    for (int nf = 0; nf < 2; nf++)
#pragma unroll
      for (int ks = 0; ks < 2; ks++) {
        int c = wn * 32 + nf * 16 + fr;
        b0[nf][ks] = *(const bf16x8*)&Bls[cur][0][c * 64 + (((ks * 4 + fg) ^ (c & 7)) << 3)];
      }
    if (more) stageA(nxt, 0, kn);
    asm volatile("s_waitcnt vmcnt(4)" ::: "memory");
    __builtin_amdgcn_s_barrier();
    asm volatile("s_waitcnt lgkmcnt(0)" ::: "memory");
    __builtin_amdgcn_sched_barrier(0);
    __builtin_amdgcn_s_setprio(1);
#pragma unroll
    for (int mf = 0; mf < 4; mf++)
#pragma unroll
      for (int nf = 0; nf < 2; nf++)
#pragma unroll
        for (int ks = 0; ks < 2; ks++)
          acc[mf][nf] =
              __builtin_amdgcn_mfma_f32_16x16x32_bf16(afr[mf][ks], b0[nf][ks], acc[mf][nf], 0, 0, 0);
    __builtin_amdgcn_s_setprio(0);
    __builtin_amdgcn_s_barrier();
    // phase 1: (0,1)
#pragma unroll
    for (int nf = 0; nf < 2; nf++)
#pragma unroll
      for (int ks = 0; ks < 2; ks++) {
        int c = wn * 32 + nf * 16 + fr;
        b1[nf][ks] = *(const bf16x8*)&Bls[cur][1][c * 64 + (((ks * 4 + fg) ^ (c & 7)) << 3)];
      }
    if (more) stageB(nxt, 0, kn);
    asm volatile("s_waitcnt vmcnt(4)" ::: "memory");
    __builtin_amdgcn_s_barrier();
    asm volatile("s_waitcnt lgkmcnt(0)" ::: "memory");
    __builtin_amdgcn_sched_barrier(0);
    __builtin_amdgcn_s_setprio(1);
#pragma unroll
    for (int mf = 0; mf < 4; mf++)
#pragma unroll
      for (int nf = 0; nf < 2; nf++)
#pragma unroll
        for (int ks = 0; ks < 2; ks++)
          acc[mf][2 + nf] =
              __builtin_amdgcn_mfma_f32_16x16x32_bf16(afr[mf][ks], b1[nf][ks], acc[mf][2 + nf], 0, 0, 0);
    __builtin_amdgcn_s_setprio(0);
    __builtin_amdgcn_s_barrier();
    // phase 2: (1,1)
#pragma unroll
    for (int mf = 0; mf < 4; mf++)
#pragma unroll
      for (int ks = 0; ks < 2; ks++) {
        int r = wm * 64 + mf * 16 + fr;
        afr[mf][ks] = *(const bf16x8*)&Als[cur][1][r * 64 + (((ks * 4 + fg) ^ (r & 7)) << 3)];
      }
    if (more) stageB(nxt, 1, kn);
    asm volatile("s_waitcnt vmcnt(4)" ::: "memory");
    __builtin_amdgcn_s_barrier();
    asm volatile("s_waitcnt lgkmcnt(0)" ::: "memory");
    __builtin_amdgcn_sched_barrier(0);
    __builtin_amdgcn_s_setprio(1);
#pragma unroll
    for (int mf = 0; mf < 4; mf++)
#pragma unroll
      for (int nf = 0; nf < 2; nf++)
#pragma unroll
        for (int ks = 0; ks < 2; ks++)
          acc[4 + mf][2 + nf] =
              __builtin_amdgcn_mfma_f32_16x16x32_bf16(afr[mf][ks], b1[nf][ks], acc[4 + mf][2 + nf], 0, 0, 0);
    __builtin_amdgcn_s_setprio(0);
    __builtin_amdgcn_s_barrier();
    // phase 3: (1,0)
    if (more) stageA(nxt, 1, kn);
    asm volatile("s_waitcnt vmcnt(4)" ::: "memory");
    __builtin_amdgcn_s_barrier();
    asm volatile("s_waitcnt lgkmcnt(0)" ::: "memory");
    __builtin_amdgcn_sched_barrier(0);
    __builtin_amdgcn_s_setprio(1);
#pragma unroll
    for (int mf = 0; mf < 4; mf++)
#pragma unroll
      for (int nf = 0; nf < 2; nf++)
#pragma unroll
        for (int ks = 0; ks < 2; ks++)
          acc[4 + mf][nf] =
              __builtin_amdgcn_mfma_f32_16x16x32_bf16(afr[mf][ks], b0[nf][ks], acc[4 + mf][nf], 0, 0, 0);
    __builtin_amdgcn_s_setprio(0);
    __builtin_amdgcn_s_barrier();
  }
  const int orow = row0 + wm * 64 + fg * 4;
  const int ocol = col0 + wn * 32 + fr;
  ushort* Pz = (ushort*)Cout + (size_t)blockIdx.z * M * N;
#pragma unroll
  for (int am = 0; am < 8; am++) {
#pragma unroll
    for (int j = 0; j < 4; j++) {
      int r = orow + (am >> 2) * 128 + (am & 3) * 16 + j;
#pragma unroll
      for (int an = 0; an < 4; an++) {
        int cidx = ocol + (an >> 1) * 128 + (an & 1) * 16;
        size_t idx = (size_t)r * N + cidx;
        float v = acc[am][an][j];
        if (EPI == 0) {
          ((ushort*)Cout)[idx] = f2bf(v);
        } else if (EPI == 2) {
          ((ushort*)Cout)[idx] = f2bf(gelu_f(v));
        } else {
          Pz[idx] = f2bf(v);
        }
      }
    }
  }
}

// ---------------- 64x64 NT GEMM (ring structure) for out-proj ----------------
template <int EPI, int BM, int BN, int DEPTH, int XR, int XC, bool CTFAST>
__global__ __launch_bounds__(256) void gemm_nt(const ushort* __restrict__ A,
                                               const ushort* __restrict__ Bw,
                                               void* __restrict__ Cout,
                                               const void* __restrict__ resid,
                                               int M, int N, int K, int Klen) {
  constexpr int WROWS = BM / 2, WCOLS = BN / 2;
  constexpr int MR = WROWS / 16, NR = WCOLS / 16;
  constexpr int ALOADS = BM / 64, BLOADS = BN / 64;
  constexpr int NLOADS = ALOADS + BLOADS;
  __shared__ __align__(16) ushort Als[DEPTH][BM * 32];
  __shared__ __align__(16) ushort Bls[DEPTH][BN * 32];
  const int tid = threadIdx.x;
  const int lane = tid & 63;
  const int w = tid >> 6;
  const int wr = w >> 1, wc = w & 1;
  const int bid = blockIdx.y * gridDim.x + blockIdx.x;
  const int xcd = bid & 7;
  const int i0 = bid >> 3;
  const int CR = gridDim.x / XR, CC = gridDim.y / XC;
  int rt, ct;
  if constexpr (CTFAST) {
    rt = (xcd % XR) * CR + (i0 / CC);
    ct = (xcd / XR) * CC + (i0 % CC);
  } else {
    rt = (xcd % XR) * CR + (i0 % CR);
    ct = (xcd / XR) * CC + (i0 / CR);
  }
  const int row0 = rt * BM;
  const int col0 = ct * BN;
  const int koff = blockIdx.z * Klen;
  const ushort* Ab = A + (size_t)row0 * K + koff;
  const ushort* Bb = Bw + (size_t)col0 * K + koff;
  const int sr = tid >> 2;
  const int scA = (((tid & 3) ^ ((tid >> 3) & 3)) * 8);
  const int fr = lane & 15;
  const int fg = lane >> 4;
  f32x4 zero = {0.f, 0.f, 0.f, 0.f};
  f32x4 acc[MR][NR];
#pragma unroll
  for (int m = 0; m < MR; m++)
#pragma unroll
    for (int n = 0; n < NR; n++) acc[m][n] = zero;

  auto stage = [&](int slot, int kt) {
#pragma unroll
    for (int i2 = 0; i2 < ALOADS; i2++)
      gload_lds16(Ab + (size_t)(sr + 64 * i2) * K + kt + scA, &Als[slot][i2 * 2048 + tid * 8]);
#pragma unroll
    for (int i2 = 0; i2 < BLOADS; i2++)
      gload_lds16(Bb + (size_t)(sr + 64 * i2) * K + kt + scA, &Bls[slot][i2 * 2048 + tid * 8]);
  };
  const int nt = Klen >> 5;
#pragma unroll
  for (int p = 0; p < DEPTH - 1; p++) stage(p, p << 5);
  int cur = 0, sbuf = DEPTH - 1;
  for (int t = 0; t < nt; t++) {
    const int ahead = nt - 1 - t;
    if constexpr (DEPTH == 3) {
      if (ahead >= 1) asm volatile("s_waitcnt vmcnt(%0)" ::"i"(NLOADS) : "memory");
      else            asm volatile("s_waitcnt vmcnt(0)" ::: "memory");
    } else if constexpr (DEPTH == 4) {
      if (ahead >= 2)      asm volatile("s_waitcnt vmcnt(%0)" ::"i"(2 * NLOADS) : "memory");
      else if (ahead == 1) asm volatile("s_waitcnt vmcnt(%0)" ::"i"(NLOADS) : "memory");
      else                 asm volatile("s_waitcnt vmcnt(0)" ::: "memory");
    } else {
      if (ahead >= 3)      asm volatile("s_waitcnt vmcnt(%0)" ::"i"(3 * NLOADS) : "memory");
      else if (ahead == 2) asm volatile("s_waitcnt vmcnt(%0)" ::"i"(2 * NLOADS) : "memory");
      else if (ahead == 1) asm volatile("s_waitcnt vmcnt(%0)" ::"i"(NLOADS) : "memory");
      else                 asm volatile("s_waitcnt vmcnt(0)" ::: "memory");
    }
    __builtin_amdgcn_s_barrier();
    if (t + DEPTH - 1 < nt) {
      stage(sbuf, (t + DEPTH - 1) << 5);
      sbuf = (sbuf == DEPTH - 1) ? 0 : sbuf + 1;
    }
    bf16x8 af[MR], bfr[NR];
#pragma unroll
    for (int m = 0; m < MR; m++) {
      int rA = wr * WROWS + m * 16 + fr;
      af[m] = *(const bf16x8*)&Als[cur][rA * 32 + ((fg ^ ((rA >> 1) & 3)) << 3)];
    }
#pragma unroll
    for (int n = 0; n < NR; n++) {
      int rB = wc * WCOLS + n * 16 + fr;
      bfr[n] = *(const bf16x8*)&Bls[cur][rB * 32 + ((fg ^ ((rB >> 1) & 3)) << 3)];
    }
#pragma unroll
    for (int m = 0; m < MR; m++)
#pragma unroll
      for (int n = 0; n < NR; n++)
        acc[m][n] = __builtin_amdgcn_mfma_f32_16x16x32_bf16(af[m], bfr[n], acc[m][n], 0, 0, 0);
    cur = (cur == DEPTH - 1) ? 0 : cur + 1;
  }
  const int orow = row0 + wr * WROWS + fg * 4;
  const int ocol = col0 + wc * WCOLS + fr;
#pragma unroll
  for (int m = 0; m < MR; m++) {
#pragma unroll
    for (int j = 0; j < 4; j++) {
      int r = orow + m * 16 + j;
#pragma unroll
      for (int n = 0; n < NR; n++) {
        int cidx = ocol + n * 16;
        size_t idx = (size_t)r * N + cidx;
        float v = acc[m][n][j];
        if (EPI == 0) {
          ((ushort*)Cout)[idx] = f2bf(v);
        } else if (EPI == 1) {
          ((ushort*)Cout)[idx] = f2bf(((const float*)resid)[idx] + v);
        } else if (EPI == 2) {
          ((ushort*)Cout)[idx] = f2bf(gelu_f(v));
        }
      }
    }
  }
}

// ---------------- split-K=4 reduce: out = bf16resid + P0+P1+P2+P3 (bf16 partials) ------
__global__ __launch_bounds__(256) void reduce_down4_kernel(const ushort* __restrict__ P,
                                                           const ushort* __restrict__ residb,
                                                           float* __restrict__ out) {
  int i = blockIdx.x * 256 + threadIdx.x;
  ushort4 r = ((const ushort4*)residb)[i];
  float4 o;
  o.x = bf2f(r.x); o.y = bf2f(r.y); o.z = bf2f(r.z); o.w = bf2f(r.w);
#pragma unroll
  for (int z = 0; z < 4; z++) {
    ushort4 p = ((const ushort4*)(P + (size_t)z * 4194304))[i];
    o.x += bf2f(p.x); o.y += bf2f(p.y); o.z += bf2f(p.z); o.w += bf2f(p.w);
  }
  ((float4*)out)[i] = o;
}

// ---------------- RoPE + cosine-sim scaling; Q pre-scaled by log2(e) ----------------
__global__ __launch_bounds__(256) void rope_kernel(const ushort* __restrict__ qkv,
                                                   const float* __restrict__ pos,
                                                   const float* __restrict__ pos_orig,
                                                   const float* __restrict__ timep,
                                                   const float* __restrict__ qk_scale,
                                                   ushort* __restrict__ qr,
                                                   ushort* __restrict__ kr) {
  int gw = (blockIdx.x * 256 + threadIdx.x) >> 6;
  int lane = threadIdx.x & 63;
  int h = gw & 15;
  int row = gw >> 4;
  int b = row >> 11;
  int l = row & (L_ - 1);
  float qv = bf2f(qkv[(size_t)row * 3072 + h * 64 + lane]);
  float kv = bf2f(qkv[(size_t)row * 3072 + 1024 + h * 64 + lane]);
  float c = 1.0f, s = 0.0f;
  if (lane < 50) {
    int idx = lane < 25 ? lane : lane - 25;
    int sg = idx / 5, d = idx % 5;
    int fi = d * 16 + h;
    float th;
    if (sg == 4) {
      th = timep[row] * __expf(-(float)fi * 0.05756462732485115f);
    } else {
      float fr = 3.14159265358979323846f * __expf((float)fi * 0.028782313662425575f);
      const float* psrc = (sg == 0 || sg == 2) ? pos_orig : pos;
      int comp = (sg < 2) ? 1 : 0;
      th = (2.0f * psrc[(size_t)row * 2 + comp] - 1.0f) * fr;
    }
    s = sinf(th);
    c = cosf(th);
  }
  int partner = lane < 25 ? lane + 25 : lane - 25;
  float qp = __shfl(qv, partner, 64);
  float kp = __shfl(kv, partner, 64);
  float yq, yk;
  if (lane < 25) { yq = qv * c - qp * s; yk = kv * c - kp * s; }
  else if (lane < 50) { yq = qv * c + qp * s; yk = kv * c + kp * s; }
  else { yq = qv; yk = kv; }
  float sq = yq * yq, sk = yk * yk;
#pragma unroll
  for (int d = 1; d < 64; d <<= 1) { sq += __shfl_xor(sq, d); sk += __shfl_xor(sk, d); }
  float scl = sqrtf(qk_scale[h]);
  float qo = yq * (scl * 1.4426950408889634f) * rsqrtf(sq + 1e-6f);
  float ko = yk * scl * rsqrtf(sk + 1e-6f);
  size_t o = ((size_t)(b * 16 + h) * L_ + l) * 64 + lane;
  qr[o] = f2bf(qo);
  kr[o] = f2bf(ko);
}

// ---------------- V transpose ----------------
__global__ __launch_bounds__(256) void vtrans_kernel(const ushort* __restrict__ qkv,
                                                     ushort* __restrict__ vT) {
  __shared__ __align__(16) ushort tile[64][72];
  int t = threadIdx.x;
  int lt = blockIdx.x;
  int bh = blockIdx.y;
  int b = bh >> 4, h = bh & 15;
  int r = t >> 3, c0 = (t & 7) * 8;
#pragma unroll
  for (int half = 0; half < 2; half++) {
    const ushort* src =
        qkv + (size_t)(b * L_ + lt * 64 + r + half * 32) * 3072 + 2048 + h * 64 + c0;
    *(uint4*)&tile[r + half * 32][c0] = *(const uint4*)src;
  }
  __syncthreads();
#pragma unroll
  for (int half = 0; half < 2; half++) {
    int dh = r + half * 32;
    unsigned p0 = (unsigned)tile[c0 + 0][dh] | ((unsigned)tile[c0 + 1][dh] << 16);
    unsigned p1 = (unsigned)tile[c0 + 2][dh] | ((unsigned)tile[c0 + 3][dh] << 16);
    unsigned p2 = (unsigned)tile[c0 + 4][dh] | ((unsigned)tile[c0 + 5][dh] << 16);
    unsigned p3 = (unsigned)tile[c0 + 6][dh] | ((unsigned)tile[c0 + 7][dh] << 16);
    uint4 o; o.x = p0; o.y = p1; o.z = p2; o.w = p3;
    *(uint4*)&vT[((size_t)bh * 64 + dh) * L_ + lt * 64 + c0] = o;
  }
}

// ---------------- Flash attention: packed-P with v_perm pack/unpack -------------------
__global__ __launch_bounds__(256) void attn_kernel(const ushort* __restrict__ qr,
                                                   const ushort* __restrict__ kr,
                                                   const ushort* __restrict__ vT,
                                                   ushort* __restrict__ attnb) {
  __shared__ __align__(16) ushort Kls[2][64 * 64];
  __shared__ __align__(16) ushort Vls[2][64 * 64];
  __shared__ __align__(16) unsigned Pls2[4][16 * 68];
  const int tid = threadIdx.x, lane = tid & 63, w = tid >> 6;
  const int bid = blockIdx.x;
  const int qp = (bid >> 3) & 15;
  const int bh = (bid & 7) | ((bid >> 7) << 3);
  const int b = bh >> 4;
  const int fr = lane & 15, fg = lane >> 4;
  const ushort* Qb0 = qr + ((size_t)bh * L_ + qp * 128 + w * 16) * 64;
  const ushort* Qb1 = Qb0 + 64 * 64;
  bf16x8 qf0[2], qf1[2];
#pragma unroll
  for (int c = 0; c < 2; c++) {
    qf0[c] = *(const bf16x8*)(Qb0 + fr * 64 + c * 32 + fg * 8);
    qf1[c] = *(const bf16x8*)(Qb1 + fr * 64 + c * 32 + fg * 8);
  }
  const ushort ob[8] = {0x3F80, 0x3F80, 0x3F80, 0x3F80, 0x3F80, 0x3F80, 0x3F80, 0x3F80};
  const bf16x8 ones = *(const bf16x8*)ob;
  f32x4 zero = {0.f, 0.f, 0.f, 0.f};
  f32x4 accO0[4], accO1[4], acc1_0 = zero, acc1_1 = zero;
#pragma unroll
  for (int n = 0; n < 4; n++) { accO0[n] = zero; accO1[n] = zero; }
  const int sr = tid >> 3;
  const int scz = (((tid & 7) ^ (sr & 7)) * 8);
  auto stage = [&](int buf, int kt) {
    gload_lds16(kr + ((size_t)bh * L_ + kt + sr) * 64 + scz, &Kls[buf][tid * 8]);
    gload_lds16(kr + ((size_t)bh * L_ + kt + 32 + sr) * 64 + scz, &Kls[buf][2048 + tid * 8]);
    gload_lds16(vT + ((size_t)bh * 64 + sr) * L_ + kt + scz, &Vls[buf][tid * 8]);
    gload_lds16(vT + ((size_t)bh * 64 + 32 + sr) * L_ + kt + scz, &Vls[buf][2048 + tid * 8]);
  };
  stage(0, 0);
  int cur = 0;
  for (int t = 0; t < (L_ >> 6); t++) {
    asm volatile("s_waitcnt vmcnt(0)" ::: "memory");
    __builtin_amdgcn_s_barrier();
    __builtin_amdgcn_sched_barrier(0);
    if (t + 1 < (L_ >> 6)) stage(cur ^ 1, (t + 1) << 6);
    f32x4 sv0[4], sv1[4];
#pragma unroll
    for (int n = 0; n < 4; n++) { sv0[n] = zero; sv1[n] = zero; }
    __builtin_amdgcn_s_setprio(1);
#pragma unroll
    for (int c = 0; c < 2; c++) {
#pragma unroll
      for (int n = 0; n < 4; n++) {
        bf16x8 kf =
            *(const bf16x8*)&Kls[cur][(n * 16 + fr) * 64 + (((c * 4 + fg) ^ (fr & 7)) << 3)];
        sv0[n] = __builtin_amdgcn_mfma_f32_16x16x32_bf16(qf0[c], kf, sv0[n], 0, 0, 0);
        sv1[n] = __builtin_amdgcn_mfma_f32_16x16x32_bf16(qf1[c], kf, sv1[n], 0, 0, 0);
      }
    }
    __builtin_amdgcn_s_setprio(0);
    // p = exp2(sv); pack qs0(lo)/qs1(hi) via v_perm (1 inst)
#pragma unroll
    for (int j = 0; j < 4; j++) {
      int rbase = (fg * 4 + j) * 68;
#pragma unroll
      for (int n = 0; n < 4; n++) {
        float p0 = __builtin_amdgcn_exp2f(sv0[n][j]);
        float p1 = __builtin_amdgcn_exp2f(sv1[n][j]);
        unsigned pk = __builtin_amdgcn_perm(__float_as_uint(p1), __float_as_uint(p0),
                                            0x07060302u);
        Pls2[w][rbase + fr + n * 16] = pk;
      }
    }
    __builtin_amdgcn_s_setprio(1);
#pragma unroll
    for (int c = 0; c < 2; c++) {
      const unsigned* pb = &Pls2[w][fr * 68 + c * 32 + fg * 8];
      uint4 qa = *(const uint4*)pb;
      uint4 qb = *(const uint4*)(pb + 4);
      uint4 u0, u1;
      u0.x = __builtin_amdgcn_perm(qa.y, qa.x, 0x05040100u);
      u1.x = __builtin_amdgcn_perm(qa.y, qa.x, 0x07060302u);
      u0.y = __builtin_amdgcn_perm(qa.w, qa.z, 0x05040100u);
      u1.y = __builtin_amdgcn_perm(qa.w, qa.z, 0x07060302u);
      u0.z = __builtin_amdgcn_perm(qb.y, qb.x, 0x05040100u);
      u1.z = __builtin_amdgcn_perm(qb.y, qb.x, 0x07060302u);
      u0.w = __builtin_amdgcn_perm(qb.w, qb.z, 0x05040100u);
      u1.w = __builtin_amdgcn_perm(qb.w, qb.z, 0x07060302u);
      bf16x8 pa0 = *(const bf16x8*)&u0;
      bf16x8 pa1 = *(const bf16x8*)&u1;
#pragma unroll
      for (int n = 0; n < 4; n++) {
        bf16x8 vb =
            *(const bf16x8*)&Vls[cur][(n * 16 + fr) * 64 + (((c * 4 + fg) ^ (fr & 7)) << 3)];
        accO0[n] = __builtin_amdgcn_mfma_f32_16x16x32_bf16(pa0, vb, accO0[n], 0, 0, 0);
        accO1[n] = __builtin_amdgcn_mfma_f32_16x16x32_bf16(pa1, vb, accO1[n], 0, 0, 0);
      }
      acc1_0 = __builtin_amdgcn_mfma_f32_16x16x32_bf16(pa0, ones, acc1_0, 0, 0, 0);
      acc1_1 = __builtin_amdgcn_mfma_f32_16x16x32_bf16(pa1, ones, acc1_1, 0, 0, 0);
    }
    __builtin_amdgcn_s_setprio(0);
    cur ^= 1;
  }
#pragma unroll
  for (int qs = 0; qs < 2; qs++) {
    const f32x4* accO = qs ? accO1 : accO0;
    const f32x4& acc1 = qs ? acc1_1 : acc1_0;
    float inv[4];
#pragma unroll
    for (int j = 0; j < 4; j++) inv[j] = __builtin_amdgcn_rcpf(acc1[j]);
#pragma unroll
    for (int n = 0; n < 4; n++) {
#pragma unroll
      for (int j = 0; j < 4; j++) {
        float o = accO[n][j] * inv[j];
        int qrow = qp * 128 + qs * 64 + w * 16 + fg * 4 + j;
        int dh = fr + n * 16;
        attnb[(size_t)(b * L_ + qrow) * 1024 + (bh & 15) * 64 + dh] = f2bf(o);
      }
    }
  }
}

extern "C" void kernel_launch(void* const* d_in, const int* in_sizes, int n_in,
                              void* d_out, int out_size, void* d_ws, size_t ws_size,
                              hipStream_t stream) {
  const float* x = (const float*)d_in[0];
  const float* pos = (const float*)d_in[1];
  const float* pos_orig = (const float*)d_in[2];
  const float* timep = (const float*)d_in[3];
  const float* w_qkv = (const float*)d_in[4];
  const float* w_out = (const float*)d_in[5];
  const float* w_up = (const float*)d_in[6];
  const float* w_down = (const float*)d_in[7];
  const float* norm1 = (const float*)d_in[8];
  const float* norm2 = (const float*)d_in[9];
  const float* qk_scale = (const float*)d_in[10];
  float* out = (float*)d_out;
  char* ws = (char*)d_ws;
  size_t off = 0;
  auto alloc = [&](size_t bytes) {
    void* p = ws + off;
    off += bytes;
    return p;
  };
  ushort* xn = (ushort*)alloc(8ull << 20);
  ushort* qkvb = (ushort*)alloc(32ull << 20);   // qkv; gelu out (down A)
  ushort* qrb = (ushort*)alloc(8ull << 20);     // q rot; down bf16 partial z=0
  ushort* krb = (ushort*)alloc(8ull << 20);     // k rot; partial z=1
  ushort* vTb = (ushort*)alloc(8ull << 20);     // vT;    partial z=2
  ushort* attnb = (ushort*)alloc(8ull << 20);   // attn;  partial z=3
  ushort* x1b = (ushort*)alloc(8ull << 20);     // bf16 residual x1
  ushort* wqkvb = (ushort*)alloc(6ull << 20);
  ushort* woutb = (ushort*)alloc(2ull << 20);
  ushort* wupb = (ushort*)alloc(8ull << 20);
  ushort* wdownb = (ushort*)alloc(8ull << 20);
  ushort* Pdown = qrb;  // 4 x 8MB bf16 down partials (qrb..attnb dead by then)

  cast_all_kernel<<<12288, 256, 0, stream>>>(w_qkv, w_out, w_up, w_down,
                                             wqkvb, woutb, wupb, wdownb);

  rmsnorm_kernel<float><<<4096, 256, 0, stream>>>(x, norm1, xn);
  gemm256<0, 4, 2><<<dim3(16, 12), 512, 0, stream>>>(xn, wqkvb, qkvb, 4096, 3072, 1024, 1024);
  rope_kernel<<<16384, 256, 0, stream>>>(qkvb, pos, pos_orig, timep, qk_scale, qrb, krb);
  vtrans_kernel<<<dim3(32, 32), 256, 0, stream>>>(qkvb, vTb);
  attn_kernel<<<512, 256, 0, stream>>>(qrb, krb, vTb, attnb);
  gemm_nt<1, 64, 64, 5, 4, 2, false><<<dim3(64, 16), 256, 0, stream>>>(
      attnb, woutb, x1b, x, 4096, 1024, 1024, 1024);
  rmsnorm_kernel<ushort><<<4096, 256, 0, stream>>>(x1b, norm2, xn);
  gemm256<2, 4, 2><<<dim3(16, 16), 512, 0, stream>>>(xn, wupb, qkvb, 4096, 4096, 1024, 1024);
  gemm256<3, 4, 2><<<dim3(16, 4, 4), 512, 0, stream>>>(qkvb, wdownb, Pdown, 4096, 1024, 4096, 1024);
  reduce_down4_kernel<<<4096, 256, 0, stream>>>(Pdown, x1b, out);
}

// Round 24
// 241.418 us; speedup vs baseline: 1.0705x; 1.0073x over previous
//
#include <hip/hip_runtime.h>

#define B_ 2
#define L_ 2048
#define D_ 1024
#define H_ 16
#define DH_ 64

typedef float f32x4 __attribute__((ext_vector_type(4)));
typedef __bf16 bf16x8 __attribute__((ext_vector_type(8)));

__device__ __forceinline__ ushort f2bf(float f) {
  unsigned u = __float_as_uint(f);
  u += 0x7fffu + ((u >> 16) & 1u);
  return (ushort)(u >> 16);
}
__device__ __forceinline__ float bf2f(ushort h) {
  return __uint_as_float(((unsigned)h) << 16);
}

__device__ __forceinline__ void gload_lds16(const void* g, void* l) {
  __builtin_amdgcn_global_load_lds(
      (const __attribute__((address_space(1))) unsigned*)g,
      (__attribute__((address_space(3))) unsigned*)l, 16, 0, 0);
}

// gelu(v) = v * sigmoid(2u), u = 0.79788456(v + 0.044715 v^3)  [exp2+rcp]
__device__ __forceinline__ float gelu_f(float v) {
  float u = 0.7978845608f * (v + 0.044715f * v * v * v);
  float e = __builtin_amdgcn_exp2f(u * -2.885390081777927f);
  return v * __builtin_amdgcn_rcpf(1.0f + e);
}

// fast sin/cos: hardware v_sin/v_cos take REVOLUTIONS; reduce with v_fract
// (periodicity-exact). |theta| <= 10*pi here -> rev <= 5, well within range.
__device__ __forceinline__ float fast_sinf(float th) {
  float rev = th * 0.15915494309189535f;
  return __builtin_amdgcn_sinf(__builtin_amdgcn_fractf(rev));
}
__device__ __forceinline__ float fast_cosf(float th) {
  float rev = th * 0.15915494309189535f;
  return __builtin_amdgcn_cosf(__builtin_amdgcn_fractf(rev));
}

// ---------------- cast f32 -> bf16, all four weights in one launch ----------------
__global__ __launch_bounds__(256) void cast_all_kernel(const float* __restrict__ w0,
                                                       const float* __restrict__ w1,
                                                       const float* __restrict__ w2,
                                                       const float* __restrict__ w3,
                                                       ushort* __restrict__ o0,
                                                       ushort* __restrict__ o1,
                                                       ushort* __restrict__ o2,
                                                       ushort* __restrict__ o3) {
  int i = blockIdx.x * 256 + threadIdx.x;
  const float* src;
  ushort* dst;
  int j = i;
  if (j < 786432) { src = w0; dst = o0; }
  else if (j < 786432 + 262144) { j -= 786432; src = w1; dst = o1; }
  else if (j < 786432 + 262144 + 1048576) { j -= 786432 + 262144; src = w2; dst = o2; }
  else { j -= 786432 + 262144 + 1048576; src = w3; dst = o3; }
  float4 v = ((const float4*)src)[j];
  ushort4 o;
  o.x = f2bf(v.x); o.y = f2bf(v.y); o.z = f2bf(v.z); o.w = f2bf(v.w);
  ((ushort4*)dst)[j] = o;
}

// ---------------- RMSNorm (T in, bf16 out), one block per row of 1024 ----------------
template <typename T>
__global__ __launch_bounds__(256) void rmsnorm_kernel(const T* __restrict__ x,
                                                      const float* __restrict__ scale,
                                                      ushort* __restrict__ out) {
  int row = blockIdx.x, t = threadIdx.x;
  float4 v;
  if constexpr (sizeof(T) == 4) {
    v = ((const float4*)((const float*)x + (size_t)row * D_))[t];
  } else {
    ushort4 u = ((const ushort4*)((const ushort*)x + (size_t)row * D_))[t];
    v.x = bf2f(u.x); v.y = bf2f(u.y); v.z = bf2f(u.z); v.w = bf2f(u.w);
  }
  float ss = v.x * v.x + v.y * v.y + v.z * v.z + v.w * v.w;
#pragma unroll
  for (int d = 1; d < 64; d <<= 1) ss += __shfl_xor(ss, d);
  __shared__ float wsum[4];
  if ((t & 63) == 0) wsum[t >> 6] = ss;
  __syncthreads();
  float tot = wsum[0] + wsum[1] + wsum[2] + wsum[3];
  float r = rsqrtf(tot * (1.0f / D_) + 1e-6f);
  float4 sc = ((const float4*)scale)[t];
  ushort4 o;
  o.x = f2bf(v.x * sc.x * r); o.y = f2bf(v.y * sc.y * r);
  o.z = f2bf(v.z * sc.z * r); o.w = f2bf(v.w * sc.w * r);
  ((ushort4*)(out + (size_t)row * D_))[t] = o;
}

// ============ 256x256 8-phase NT GEMM (m194-m201 template, plain HIP) ============
template <int EPI, int XR, int XC>
__global__ __launch_bounds__(512, 2) void gemm256(const ushort* __restrict__ A,
                                                  const ushort* __restrict__ Bw,
                                                  void* __restrict__ Cout,
                                                  int M, int N, int K, int Klen) {
  __shared__ __align__(16) ushort Als[2][2][128 * 64];
  __shared__ __align__(16) ushort Bls[2][2][128 * 64];
  const int tid = threadIdx.x;
  const int lane = tid & 63;
  const int w = tid >> 6;
  const int wm = w >> 2, wn = w & 3;
  const int fr = lane & 15, fg = lane >> 4;
  const int bid = blockIdx.y * gridDim.x + blockIdx.x;
  const int xcd = bid & 7, i0 = bid >> 3;
  const int CR = gridDim.x / XR, CC = gridDim.y / XC;
  const int rt = (xcd % XR) * CR + (i0 % CR);
  const int ct = (xcd / XR) * CC + (i0 / CR);
  const int row0 = rt * 256, col0 = ct * 256;
  const int koff = blockIdx.z * Klen;
  const ushort* Ab = A + (size_t)row0 * K + koff;
  const ushort* Bb = Bw + (size_t)col0 * K + koff;
  const int srow = tid >> 3;
  const int sxor = ((tid & 7) ^ (srow & 7)) * 8;

  f32x4 acc[8][4];
  f32x4 zero = {0.f, 0.f, 0.f, 0.f};
#pragma unroll
  for (int m = 0; m < 8; m++)
#pragma unroll
    for (int n = 0; n < 4; n++) acc[m][n] = zero;

  auto stageA = [&](int buf, int half, int kt) {
#pragma unroll
    for (int i = 0; i < 2; i++)
      gload_lds16(Ab + (size_t)(half * 128 + i * 64 + srow) * K + kt + sxor,
                  &Als[buf][half][i * 4096 + tid * 8]);
  };
  auto stageB = [&](int buf, int half, int kt) {
#pragma unroll
    for (int i = 0; i < 2; i++)
      gload_lds16(Bb + (size_t)(half * 128 + i * 64 + srow) * K + kt + sxor,
                  &Bls[buf][half][i * 4096 + tid * 8]);
  };
  const int nt = Klen >> 6;
  stageA(0, 0, 0); stageB(0, 0, 0); stageB(0, 1, 0); stageA(0, 1, 0);
  asm volatile("s_waitcnt vmcnt(0)" ::: "memory");
  __builtin_amdgcn_s_barrier();

  bf16x8 afr[4][2], b0[2][2], b1[2][2];
  for (int t = 0; t < nt; t++) {
    const int cur = t & 1, nxt = cur ^ 1;
    const int kn = (t + 1) << 6;
    const bool more = (t + 1 < nt);
    // phase 0: (0,0)
#pragma unroll
    for (int mf = 0; mf < 4; mf++)
#pragma unroll
      for (int ks = 0; ks < 2; ks++) {
        int r = wm * 64 + mf * 16 + fr;
        afr[mf][ks] = *(const bf16x8*)&Als[cur][0][r * 64 + (((ks * 4 + fg) ^ (r & 7)) << 3)];
      }
#pragma unroll
    for (int nf = 0; nf < 2; nf++)
#pragma unroll
      for (int ks = 0; ks < 2; ks++) {
        int c = wn * 32 + nf * 16 + fr;
        b0[nf][ks] = *(const bf16x8*)&Bls[cur][0][c * 64 + (((ks * 4 + fg) ^ (c & 7)) << 3)];
      }
    if (more) stageA(nxt, 0, kn);
    asm volatile("s_waitcnt vmcnt(4)" ::: "memory");
    __builtin_amdgcn_s_barrier();
    asm volatile("s_waitcnt lgkmcnt(0)" ::: "memory");
    __builtin_amdgcn_sched_barrier(0);
    __builtin_amdgcn_s_setprio(1);
#pragma unroll
    for (int mf = 0; mf < 4; mf++)
#pragma unroll
      for (int nf = 0; nf < 2; nf++)
#pragma unroll
        for (int ks = 0; ks < 2; ks++)
          acc[mf][nf] =
              __builtin_amdgcn_mfma_f32_16x16x32_bf16(afr[mf][ks], b0[nf][ks], acc[mf][nf], 0, 0, 0);
    __builtin_amdgcn_s_setprio(0);
    __builtin_amdgcn_s_barrier();
    // phase 1: (0,1)
#pragma unroll
    for (int nf = 0; nf < 2; nf++)
#pragma unroll
      for (int ks = 0; ks < 2; ks++) {
        int c = wn * 32 + nf * 16 + fr;
        b1[nf][ks] = *(const bf16x8*)&Bls[cur][1][c * 64 + (((ks * 4 + fg) ^ (c & 7)) << 3)];
      }
    if (more) stageB(nxt, 0, kn);
    asm volatile("s_waitcnt vmcnt(4)" ::: "memory");
    __builtin_amdgcn_s_barrier();
    asm volatile("s_waitcnt lgkmcnt(0)" ::: "memory");
    __builtin_amdgcn_sched_barrier(0);
    __builtin_amdgcn_s_setprio(1);
#pragma unroll
    for (int mf = 0; mf < 4; mf++)
#pragma unroll
      for (int nf = 0; nf < 2; nf++)
#pragma unroll
        for (int ks = 0; ks < 2; ks++)
          acc[mf][2 + nf] =
              __builtin_amdgcn_mfma_f32_16x16x32_bf16(afr[mf][ks], b1[nf][ks], acc[mf][2 + nf], 0, 0, 0);
    __builtin_amdgcn_s_setprio(0);
    __builtin_amdgcn_s_barrier();
    // phase 2: (1,1)
#pragma unroll
    for (int mf = 0; mf < 4; mf++)
#pragma unroll
      for (int ks = 0; ks < 2; ks++) {
        int r = wm * 64 + mf * 16 + fr;
        afr[mf][ks] = *(const bf16x8*)&Als[cur][1][r * 64 + (((ks * 4 + fg) ^ (r & 7)) << 3)];
      }
    if (more) stageB(nxt, 1, kn);
    asm volatile("s_waitcnt vmcnt(4)" ::: "memory");
    __builtin_amdgcn_s_barrier();
    asm volatile("s_waitcnt lgkmcnt(0)" ::: "memory");
    __builtin_amdgcn_sched_barrier(0);
    __builtin_amdgcn_s_setprio(1);
#pragma unroll
    for (int mf = 0; mf < 4; mf++)
#pragma unroll
      for (int nf = 0; nf < 2; nf++)
#pragma unroll
        for (int ks = 0; ks < 2; ks++)
          acc[4 + mf][2 + nf] =
              __builtin_amdgcn_mfma_f32_16x16x32_bf16(afr[mf][ks], b1[nf][ks], acc[4 + mf][2 + nf], 0, 0, 0);
    __builtin_amdgcn_s_setprio(0);
    __builtin_amdgcn_s_barrier();
    // phase 3: (1,0)
    if (more) stageA(nxt, 1, kn);
    asm volatile("s_waitcnt vmcnt(4)" ::: "memory");
    __builtin_amdgcn_s_barrier();
    asm volatile("s_waitcnt lgkmcnt(0)" ::: "memory");
    __builtin_amdgcn_sched_barrier(0);
    __builtin_amdgcn_s_setprio(1);
#pragma unroll
    for (int mf = 0; mf < 4; mf++)
#pragma unroll
      for (int nf = 0; nf < 2; nf++)
#pragma unroll
        for (int ks = 0; ks < 2; ks++)
          acc[4 + mf][nf] =
              __builtin_amdgcn_mfma_f32_16x16x32_bf16(afr[mf][ks], b0[nf][ks], acc[4 + mf][nf], 0, 0, 0);
    __builtin_amdgcn_s_setprio(0);
    __builtin_amdgcn_s_barrier();
  }
  const int orow = row0 + wm * 64 + fg * 4;
  const int ocol = col0 + wn * 32 + fr;
  ushort* Pz = (ushort*)Cout + (size_t)blockIdx.z * M * N;
#pragma unroll
  for (int am = 0; am < 8; am++) {
#pragma unroll
    for (int j = 0; j < 4; j++) {
      int r = orow + (am >> 2) * 128 + (am & 3) * 16 + j;
#pragma unroll
      for (int an = 0; an < 4; an++) {
        int cidx = ocol + (an >> 1) * 128 + (an & 1) * 16;
        size_t idx = (size_t)r * N + cidx;
        float v = acc[am][an][j];
        if (EPI == 0) {
          ((ushort*)Cout)[idx] = f2bf(v);
        } else if (EPI == 2) {
          ((ushort*)Cout)[idx] = f2bf(gelu_f(v));
        } else {
          Pz[idx] = f2bf(v);
        }
      }
    }
  }
}

// ---------------- 64x64 NT GEMM (ring structure) for out-proj ----------------
template <int EPI, int BM, int BN, int DEPTH, int XR, int XC, bool CTFAST>
__global__ __launch_bounds__(256) void gemm_nt(const ushort* __restrict__ A,
                                               const ushort* __restrict__ Bw,
                                               void* __restrict__ Cout,
                                               const void* __restrict__ resid,
                                               int M, int N, int K, int Klen) {
  constexpr int WROWS = BM / 2, WCOLS = BN / 2;
  constexpr int MR = WROWS / 16, NR = WCOLS / 16;
  constexpr int ALOADS = BM / 64, BLOADS = BN / 64;
  constexpr int NLOADS = ALOADS + BLOADS;
  __shared__ __align__(16) ushort Als[DEPTH][BM * 32];
  __shared__ __align__(16) ushort Bls[DEPTH][BN * 32];
  const int tid = threadIdx.x;
  const int lane = tid & 63;
  const int w = tid >> 6;
  const int wr = w >> 1, wc = w & 1;
  const int bid = blockIdx.y * gridDim.x + blockIdx.x;
  const int xcd = bid & 7;
  const int i0 = bid >> 3;
  const int CR = gridDim.x / XR, CC = gridDim.y / XC;
  int rt, ct;
  if constexpr (CTFAST) {
    rt = (xcd % XR) * CR + (i0 / CC);
    ct = (xcd / XR) * CC + (i0 % CC);
  } else {
    rt = (xcd % XR) * CR + (i0 % CR);
    ct = (xcd / XR) * CC + (i0 / CR);
  }
  const int row0 = rt * BM;
  const int col0 = ct * BN;
  const int koff = blockIdx.z * Klen;
  const ushort* Ab = A + (size_t)row0 * K + koff;
  const ushort* Bb = Bw + (size_t)col0 * K + koff;
  const int sr = tid >> 2;
  const int scA = (((tid & 3) ^ ((tid >> 3) & 3)) * 8);
  const int fr = lane & 15;
  const int fg = lane >> 4;
  f32x4 zero = {0.f, 0.f, 0.f, 0.f};
  f32x4 acc[MR][NR];
#pragma unroll
  for (int m = 0; m < MR; m++)
#pragma unroll
    for (int n = 0; n < NR; n++) acc[m][n] = zero;

  auto stage = [&](int slot, int kt) {
#pragma unroll
    for (int i2 = 0; i2 < ALOADS; i2++)
      gload_lds16(Ab + (size_t)(sr + 64 * i2) * K + kt + scA, &Als[slot][i2 * 2048 + tid * 8]);
#pragma unroll
    for (int i2 = 0; i2 < BLOADS; i2++)
      gload_lds16(Bb + (size_t)(sr + 64 * i2) * K + kt + scA, &Bls[slot][i2 * 2048 + tid * 8]);
  };
  const int nt = Klen >> 5;
#pragma unroll
  for (int p = 0; p < DEPTH - 1; p++) stage(p, p << 5);
  int cur = 0, sbuf = DEPTH - 1;
  for (int t = 0; t < nt; t++) {
    const int ahead = nt - 1 - t;
    if constexpr (DEPTH == 3) {
      if (ahead >= 1) asm volatile("s_waitcnt vmcnt(%0)" ::"i"(NLOADS) : "memory");
      else            asm volatile("s_waitcnt vmcnt(0)" ::: "memory");
    } else if constexpr (DEPTH == 4) {
      if (ahead >= 2)      asm volatile("s_waitcnt vmcnt(%0)" ::"i"(2 * NLOADS) : "memory");
      else if (ahead == 1) asm volatile("s_waitcnt vmcnt(%0)" ::"i"(NLOADS) : "memory");
      else                 asm volatile("s_waitcnt vmcnt(0)" ::: "memory");
    } else {
      if (ahead >= 3)      asm volatile("s_waitcnt vmcnt(%0)" ::"i"(3 * NLOADS) : "memory");
      else if (ahead == 2) asm volatile("s_waitcnt vmcnt(%0)" ::"i"(2 * NLOADS) : "memory");
      else if (ahead == 1) asm volatile("s_waitcnt vmcnt(%0)" ::"i"(NLOADS) : "memory");
      else                 asm volatile("s_waitcnt vmcnt(0)" ::: "memory");
    }
    __builtin_amdgcn_s_barrier();
    if (t + DEPTH - 1 < nt) {
      stage(sbuf, (t + DEPTH - 1) << 5);
      sbuf = (sbuf == DEPTH - 1) ? 0 : sbuf + 1;
    }
    bf16x8 af[MR], bfr[NR];
#pragma unroll
    for (int m = 0; m < MR; m++) {
      int rA = wr * WROWS + m * 16 + fr;
      af[m] = *(const bf16x8*)&Als[cur][rA * 32 + ((fg ^ ((rA >> 1) & 3)) << 3)];
    }
#pragma unroll
    for (int n = 0; n < NR; n++) {
      int rB = wc * WCOLS + n * 16 + fr;
      bfr[n] = *(const bf16x8*)&Bls[cur][rB * 32 + ((fg ^ ((rB >> 1) & 3)) << 3)];
    }
#pragma unroll
    for (int m = 0; m < MR; m++)
#pragma unroll
      for (int n = 0; n < NR; n++)
        acc[m][n] = __builtin_amdgcn_mfma_f32_16x16x32_bf16(af[m], bfr[n], acc[m][n], 0, 0, 0);
    cur = (cur == DEPTH - 1) ? 0 : cur + 1;
  }
  const int orow = row0 + wr * WROWS + fg * 4;
  const int ocol = col0 + wc * WCOLS + fr;
#pragma unroll
  for (int m = 0; m < MR; m++) {
#pragma unroll
    for (int j = 0; j < 4; j++) {
      int r = orow + m * 16 + j;
#pragma unroll
      for (int n = 0; n < NR; n++) {
        int cidx = ocol + n * 16;
        size_t idx = (size_t)r * N + cidx;
        float v = acc[m][n][j];
        if (EPI == 0) {
          ((ushort*)Cout)[idx] = f2bf(v);
        } else if (EPI == 1) {
          ((ushort*)Cout)[idx] = f2bf(((const float*)resid)[idx] + v);
        } else if (EPI == 2) {
          ((ushort*)Cout)[idx] = f2bf(gelu_f(v));
        }
      }
    }
  }
}

// ---------------- split-K=4 reduce: out = bf16resid + P0+P1+P2+P3 (bf16 partials) ------
__global__ __launch_bounds__(256) void reduce_down4_kernel(const ushort* __restrict__ P,
                                                           const ushort* __restrict__ residb,
                                                           float* __restrict__ out) {
  int i = blockIdx.x * 256 + threadIdx.x;
  ushort4 r = ((const ushort4*)residb)[i];
  float4 o;
  o.x = bf2f(r.x); o.y = bf2f(r.y); o.z = bf2f(r.z); o.w = bf2f(r.w);
#pragma unroll
  for (int z = 0; z < 4; z++) {
    ushort4 p = ((const ushort4*)(P + (size_t)z * 4194304))[i];
    o.x += bf2f(p.x); o.y += bf2f(p.y); o.z += bf2f(p.z); o.w += bf2f(p.w);
  }
  ((float4*)out)[i] = o;
}

// ---------------- RoPE + cosine-sim scaling; Q pre-scaled by log2(e) ----------------
// sin/cos via hardware v_sin/v_cos (revolutions + fract reduction): 3 ops vs ~40 libm.
__global__ __launch_bounds__(256) void rope_kernel(const ushort* __restrict__ qkv,
                                                   const float* __restrict__ pos,
                                                   const float* __restrict__ pos_orig,
                                                   const float* __restrict__ timep,
                                                   const float* __restrict__ qk_scale,
                                                   ushort* __restrict__ qr,
                                                   ushort* __restrict__ kr) {
  int gw = (blockIdx.x * 256 + threadIdx.x) >> 6;
  int lane = threadIdx.x & 63;
  int h = gw & 15;
  int row = gw >> 4;
  int b = row >> 11;
  int l = row & (L_ - 1);
  float qv = bf2f(qkv[(size_t)row * 3072 + h * 64 + lane]);
  float kv = bf2f(qkv[(size_t)row * 3072 + 1024 + h * 64 + lane]);
  float c = 1.0f, s = 0.0f;
  if (lane < 50) {
    int idx = lane < 25 ? lane : lane - 25;
    int sg = idx / 5, d = idx % 5;
    int fi = d * 16 + h;
    float th;
    if (sg == 4) {
      th = timep[row] * __expf(-(float)fi * 0.05756462732485115f);
    } else {
      float fr = 3.14159265358979323846f * __expf((float)fi * 0.028782313662425575f);
      const float* psrc = (sg == 0 || sg == 2) ? pos_orig : pos;
      int comp = (sg < 2) ? 1 : 0;
      th = (2.0f * psrc[(size_t)row * 2 + comp] - 1.0f) * fr;
    }
    s = fast_sinf(th);
    c = fast_cosf(th);
  }
  int partner = lane < 25 ? lane + 25 : lane - 25;
  float qp = __shfl(qv, partner, 64);
  float kp = __shfl(kv, partner, 64);
  float yq, yk;
  if (lane < 25) { yq = qv * c - qp * s; yk = kv * c - kp * s; }
  else if (lane < 50) { yq = qv * c + qp * s; yk = kv * c + kp * s; }
  else { yq = qv; yk = kv; }
  float sq = yq * yq, sk = yk * yk;
#pragma unroll
  for (int d = 1; d < 64; d <<= 1) { sq += __shfl_xor(sq, d); sk += __shfl_xor(sk, d); }
  float scl = sqrtf(qk_scale[h]);
  float qo = yq * (scl * 1.4426950408889634f) * rsqrtf(sq + 1e-6f);
  float ko = yk * scl * rsqrtf(sk + 1e-6f);
  size_t o = ((size_t)(b * 16 + h) * L_ + l) * 64 + lane;
  qr[o] = f2bf(qo);
  kr[o] = f2bf(ko);
}

// ---------------- V transpose ----------------
__global__ __launch_bounds__(256) void vtrans_kernel(const ushort* __restrict__ qkv,
                                                     ushort* __restrict__ vT) {
  __shared__ __align__(16) ushort tile[64][72];
  int t = threadIdx.x;
  int lt = blockIdx.x;
  int bh = blockIdx.y;
  int b = bh >> 4, h = bh & 15;
  int r = t >> 3, c0 = (t & 7) * 8;
#pragma unroll
  for (int half = 0; half < 2; half++) {
    const ushort* src =
        qkv + (size_t)(b * L_ + lt * 64 + r + half * 32) * 3072 + 2048 + h * 64 + c0;
    *(uint4*)&tile[r + half * 32][c0] = *(const uint4*)src;
  }
  __syncthreads();
#pragma unroll
  for (int half = 0; half < 2; half++) {
    int dh = r + half * 32;
    unsigned p0 = (unsigned)tile[c0 + 0][dh] | ((unsigned)tile[c0 + 1][dh] << 16);
    unsigned p1 = (unsigned)tile[c0 + 2][dh] | ((unsigned)tile[c0 + 3][dh] << 16);
    unsigned p2 = (unsigned)tile[c0 + 4][dh] | ((unsigned)tile[c0 + 5][dh] << 16);
    unsigned p3 = (unsigned)tile[c0 + 6][dh] | ((unsigned)tile[c0 + 7][dh] << 16);
    uint4 o; o.x = p0; o.y = p1; o.z = p2; o.w = p3;
    *(uint4*)&vT[((size_t)bh * 64 + dh) * L_ + lt * 64 + c0] = o;
  }
}

// ---------------- Flash attention: packed-P with v_perm pack/unpack -------------------
__global__ __launch_bounds__(256) void attn_kernel(const ushort* __restrict__ qr,
                                                   const ushort* __restrict__ kr,
                                                   const ushort* __restrict__ vT,
                                                   ushort* __restrict__ attnb) {
  __shared__ __align__(16) ushort Kls[2][64 * 64];
  __shared__ __align__(16) ushort Vls[2][64 * 64];
  __shared__ __align__(16) unsigned Pls2[4][16 * 68];
  const int tid = threadIdx.x, lane = tid & 63, w = tid >> 6;
  const int bid = blockIdx.x;
  const int qp = (bid >> 3) & 15;
  const int bh = (bid & 7) | ((bid >> 7) << 3);
  const int b = bh >> 4;
  const int fr = lane & 15, fg = lane >> 4;
  const ushort* Qb0 = qr + ((size_t)bh * L_ + qp * 128 + w * 16) * 64;
  const ushort* Qb1 = Qb0 + 64 * 64;
  bf16x8 qf0[2], qf1[2];
#pragma unroll
  for (int c = 0; c < 2; c++) {
    qf0[c] = *(const bf16x8*)(Qb0 + fr * 64 + c * 32 + fg * 8);
    qf1[c] = *(const bf16x8*)(Qb1 + fr * 64 + c * 32 + fg * 8);
  }
  const ushort ob[8] = {0x3F80, 0x3F80, 0x3F80, 0x3F80, 0x3F80, 0x3F80, 0x3F80, 0x3F80};
  const bf16x8 ones = *(const bf16x8*)ob;
  f32x4 zero = {0.f, 0.f, 0.f, 0.f};
  f32x4 accO0[4], accO1[4], acc1_0 = zero, acc1_1 = zero;
#pragma unroll
  for (int n = 0; n < 4; n++) { accO0[n] = zero; accO1[n] = zero; }
  const int sr = tid >> 3;
  const int scz = (((tid & 7) ^ (sr & 7)) * 8);
  auto stage = [&](int buf, int kt) {
    gload_lds16(kr + ((size_t)bh * L_ + kt + sr) * 64 + scz, &Kls[buf][tid * 8]);
    gload_lds16(kr + ((size_t)bh * L_ + kt + 32 + sr) * 64 + scz, &Kls[buf][2048 + tid * 8]);
    gload_lds16(vT + ((size_t)bh * 64 + sr) * L_ + kt + scz, &Vls[buf][tid * 8]);
    gload_lds16(vT + ((size_t)bh * 64 + 32 + sr) * L_ + kt + scz, &Vls[buf][2048 + tid * 8]);
  };
  stage(0, 0);
  int cur = 0;
  for (int t = 0; t < (L_ >> 6); t++) {
    asm volatile("s_waitcnt vmcnt(0)" ::: "memory");
    __builtin_amdgcn_s_barrier();
    __builtin_amdgcn_sched_barrier(0);
    if (t + 1 < (L_ >> 6)) stage(cur ^ 1, (t + 1) << 6);
    f32x4 sv0[4], sv1[4];
#pragma unroll
    for (int n = 0; n < 4; n++) { sv0[n] = zero; sv1[n] = zero; }
    __builtin_amdgcn_s_setprio(1);
#pragma unroll
    for (int c = 0; c < 2; c++) {
#pragma unroll
      for (int n = 0; n < 4; n++) {
        bf16x8 kf =
            *(const bf16x8*)&Kls[cur][(n * 16 + fr) * 64 + (((c * 4 + fg) ^ (fr & 7)) << 3)];
        sv0[n] = __builtin_amdgcn_mfma_f32_16x16x32_bf16(qf0[c], kf, sv0[n], 0, 0, 0);
        sv1[n] = __builtin_amdgcn_mfma_f32_16x16x32_bf16(qf1[c], kf, sv1[n], 0, 0, 0);
      }
    }
    __builtin_amdgcn_s_setprio(0);
    // p = exp2(sv); pack qs0(lo)/qs1(hi) via v_perm (1 inst)
#pragma unroll
    for (int j = 0; j < 4; j++) {
      int rbase = (fg * 4 + j) * 68;
#pragma unroll
      for (int n = 0; n < 4; n++) {
        float p0 = __builtin_amdgcn_exp2f(sv0[n][j]);
        float p1 = __builtin_amdgcn_exp2f(sv1[n][j]);
        unsigned pk = __builtin_amdgcn_perm(__float_as_uint(p1), __float_as_uint(p0),
                                            0x07060302u);
        Pls2[w][rbase + fr + n * 16] = pk;
      }
    }
    __builtin_amdgcn_s_setprio(1);
#pragma unroll
    for (int c = 0; c < 2; c++) {
      const unsigned* pb = &Pls2[w][fr * 68 + c * 32 + fg * 8];
      uint4 qa = *(const uint4*)pb;
      uint4 qb = *(const uint4*)(pb + 4);
      uint4 u0, u1;
      u0.x = __builtin_amdgcn_perm(qa.y, qa.x, 0x05040100u);
      u1.x = __builtin_amdgcn_perm(qa.y, qa.x, 0x07060302u);
      u0.y = __builtin_amdgcn_perm(qa.w, qa.z, 0x05040100u);
      u1.y = __builtin_amdgcn_perm(qa.w, qa.z, 0x07060302u);
      u0.z = __builtin_amdgcn_perm(qb.y, qb.x, 0x05040100u);
      u1.z = __builtin_amdgcn_perm(qb.y, qb.x, 0x07060302u);
      u0.w = __builtin_amdgcn_perm(qb.w, qb.z, 0x05040100u);
      u1.w = __builtin_amdgcn_perm(qb.w, qb.z, 0x07060302u);
      bf16x8 pa0 = *(const bf16x8*)&u0;
      bf16x8 pa1 = *(const bf16x8*)&u1;
#pragma unroll
      for (int n = 0; n < 4; n++) {
        bf16x8 vb =
            *(const bf16x8*)&Vls[cur][(n * 16 + fr) * 64 + (((c * 4 + fg) ^ (fr & 7)) << 3)];
        accO0[n] = __builtin_amdgcn_mfma_f32_16x16x32_bf16(pa0, vb, accO0[n], 0, 0, 0);
        accO1[n] = __builtin_amdgcn_mfma_f32_16x16x32_bf16(pa1, vb, accO1[n], 0, 0, 0);
      }
      acc1_0 = __builtin_amdgcn_mfma_f32_16x16x32_bf16(pa0, ones, acc1_0, 0, 0, 0);
      acc1_1 = __builtin_amdgcn_mfma_f32_16x16x32_bf16(pa1, ones, acc1_1, 0, 0, 0);
    }
    __builtin_amdgcn_s_setprio(0);
    cur ^= 1;
  }
#pragma unroll
  for (int qs = 0; qs < 2; qs++) {
    const f32x4* accO = qs ? accO1 : accO0;
    const f32x4& acc1 = qs ? acc1_1 : acc1_0;
    float inv[4];
#pragma unroll
    for (int j = 0; j < 4; j++) inv[j] = __builtin_amdgcn_rcpf(acc1[j]);
#pragma unroll
    for (int n = 0; n < 4; n++) {
#pragma unroll
      for (int j = 0; j < 4; j++) {
        float o = accO[n][j] * inv[j];
        int qrow = qp * 128 + qs * 64 + w * 16 + fg * 4 + j;
        int dh = fr + n * 16;
        attnb[(size_t)(b * L_ + qrow) * 1024 + (bh & 15) * 64 + dh] = f2bf(o);
      }
    }
  }
}

extern "C" void kernel_launch(void* const* d_in, const int* in_sizes, int n_in,
                              void* d_out, int out_size, void* d_ws, size_t ws_size,
                              hipStream_t stream) {
  const float* x = (const float*)d_in[0];
  const float* pos = (const float*)d_in[1];
  const float* pos_orig = (const float*)d_in[2];
  const float* timep = (const float*)d_in[3];
  const float* w_qkv = (const float*)d_in[4];
  const float* w_out = (const float*)d_in[5];
  const float* w_up = (const float*)d_in[6];
  const float* w_down = (const float*)d_in[7];
  const float* norm1 = (const float*)d_in[8];
  const float* norm2 = (const float*)d_in[9];
  const float* qk_scale = (const float*)d_in[10];
  float* out = (float*)d_out;
  char* ws = (char*)d_ws;
  size_t off = 0;
  auto alloc = [&](size_t bytes) {
    void* p = ws + off;
    off += bytes;
    return p;
  };
  ushort* xn = (ushort*)alloc(8ull << 20);
  ushort* qkvb = (ushort*)alloc(32ull << 20);   // qkv; gelu out (down A)
  ushort* qrb = (ushort*)alloc(8ull << 20);     // q rot; down bf16 partial z=0
  ushort* krb = (ushort*)alloc(8ull << 20);     // k rot; partial z=1
  ushort* vTb = (ushort*)alloc(8ull << 20);     // vT;    partial z=2
  ushort* attnb = (ushort*)alloc(8ull << 20);   // attn;  partial z=3
  ushort* x1b = (ushort*)alloc(8ull << 20);     // bf16 residual x1
  ushort* wqkvb = (ushort*)alloc(6ull << 20);
  ushort* woutb = (ushort*)alloc(2ull << 20);
  ushort* wupb = (ushort*)alloc(8ull << 20);
  ushort* wdownb = (ushort*)alloc(8ull << 20);
  ushort* Pdown = qrb;  // 4 x 8MB bf16 down partials (qrb..attnb dead by then)

  cast_all_kernel<<<12288, 256, 0, stream>>>(w_qkv, w_out, w_up, w_down,
                                             wqkvb, woutb, wupb, wdownb);

  rmsnorm_kernel<float><<<4096, 256, 0, stream>>>(x, norm1, xn);
  gemm256<0, 4, 2><<<dim3(16, 12), 512, 0, stream>>>(xn, wqkvb, qkvb, 4096, 3072, 1024, 1024);
  rope_kernel<<<16384, 256, 0, stream>>>(qkvb, pos, pos_orig, timep, qk_scale, qrb, krb);
  vtrans_kernel<<<dim3(32, 32), 256, 0, stream>>>(qkvb, vTb);
  attn_kernel<<<512, 256, 0, stream>>>(qrb, krb, vTb, attnb);
  gemm_nt<1, 64, 64, 5, 4, 2, false><<<dim3(64, 16), 256, 0, stream>>>(
      attnb, woutb, x1b, x, 4096, 1024, 1024, 1024);
  rmsnorm_kernel<ushort><<<4096, 256, 0, stream>>>(x1b, norm2, xn);
  gemm256<2, 4, 2><<<dim3(16, 16), 512, 0, stream>>>(xn, wupb, qkvb, 4096, 4096, 1024, 1024);
  gemm256<3, 4, 2><<<dim3(16, 4, 4), 512, 0, stream>>>(qkvb, wdownb, Pdown, 4096, 1024, 4096, 1024);
  reduce_down4_kernel<<<4096, 256, 0, stream>>>(Pdown, x1b, out);
}